// Round 6
// baseline (2276.154 us; speedup 1.0000x reference)
//
#include <hip/hip_runtime.h>

// ---- problem dims (fixed by reference) ----
#define V_ 30000
#define D_ 300
#define DP_ 320
#define T_ 24
#define H_ 256
#define NT_ 6000
#define NU_ 4000
#define N_ 10000
#define F_ 512
#define Z_ 256
#define E_ 80000
#define B_ 2000
#define H1_ 64
#define H2_ 100
#define HEADS_ 8
#define E2_ (E_ + N_)
#define TCH_ 4
#define YB_ 47          // row-blocks per layer in rec grid (47*128 >= 6000)

typedef __bf16 bf16_t;
typedef bf16_t bf16x8 __attribute__((ext_vector_type(8)));
typedef float  f32x4  __attribute__((ext_vector_type(4)));

// async global->LDS, 16B per lane; lds dest = base + lane*16 (wave-uniform base)
__device__ __forceinline__ void gll16(const bf16_t* g, bf16_t* l)
{
    __builtin_amdgcn_global_load_lds(
        (const __attribute__((address_space(1))) void*)g,
        (__attribute__((address_space(3))) void*)l, 16, 0, 0);
}

// =======================================================================
// 128x128 MFMA GEMM, global_load_lds staging: C = A[M,K] @ B[N,K]^T (+bias)
// LDS chunk-major layout: slot i = c*128+row holds A[row][k0+c*8 .. +8)
// (c = 8-elem k-chunk). Issue (wave,j) stages slots [wave*128+j*64, +64),
// lane l -> slot base+l, global addr = row-ptr + c*8 + k0. Fragment read:
// chunk == quad -> ds_read_b128 at (quad*128+row)*8, rows*16B -> <=2-way
// bank aliasing (free). GM=1: A rows gathered (embedding lookup).
// =======================================================================
template<int GM, bool OUTBF>
__global__ __launch_bounds__(256) void mfma_gemm(
    const bf16_t* __restrict__ A, const bf16_t* __restrict__ B,
    const float* __restrict__ bias, float* __restrict__ Cf,
    bf16_t* __restrict__ Cb, int M, int N, int K, int ldc,
    const int* __restrict__ gtok, int t0)
{
    __shared__ __align__(16) bf16_t As[512 * 8];
    __shared__ __align__(16) bf16_t Bs[512 * 8];
    const int tid  = (int)threadIdx.x;
    const int wave = tid >> 6, lane = tid & 63;
    const int quad = lane >> 4, l16 = lane & 15;
    const int mq = (wave & 1) * 64, nq = (wave >> 1) * 64;
    const int mbase = blockIdx.y * 128, nbase = blockIdx.x * 128;

    const bf16_t* agp[2];
    const bf16_t* bgp[2];
#pragma unroll
    for (int j = 0; j < 2; j++) {
        int i = wave * 128 + j * 64 + lane;
        int c = i >> 7, row = i & 127;
        int r = mbase + row; if (r >= M) r = M - 1;
        int src = (GM == 1) ? gtok[(r % NT_) * T_ + t0 + (r / NT_)] : r;
        agp[j] = A + (size_t)src * K + c * 8;
        int rb = nbase + row; if (rb >= N) rb = N - 1;
        bgp[j] = B + (size_t)rb * K + c * 8;
    }
    bf16_t* asl0 = As + (size_t)(wave * 128) * 8;
    bf16_t* asl1 = As + (size_t)(wave * 128 + 64) * 8;
    bf16_t* bsl0 = Bs + (size_t)(wave * 128) * 8;
    bf16_t* bsl1 = Bs + (size_t)(wave * 128 + 64) * 8;

    f32x4 acc[4][4];
#pragma unroll
    for (int mi = 0; mi < 4; mi++)
#pragma unroll
        for (int ni = 0; ni < 4; ni++) acc[mi][ni] = (f32x4){0.f, 0.f, 0.f, 0.f};

    for (int k0 = 0; k0 < K; k0 += 32) {
        __syncthreads();
        gll16(agp[0] + k0, asl0);
        gll16(agp[1] + k0, asl1);
        gll16(bgp[0] + k0, bsl0);
        gll16(bgp[1] + k0, bsl1);
        __syncthreads();
        bf16x8 afr[4], bfr[4];
#pragma unroll
        for (int mi = 0; mi < 4; mi++)
            afr[mi] = *(const bf16x8*)(As + (size_t)(quad * 128 + mq + mi * 16 + l16) * 8);
#pragma unroll
        for (int ni = 0; ni < 4; ni++)
            bfr[ni] = *(const bf16x8*)(Bs + (size_t)(quad * 128 + nq + ni * 16 + l16) * 8);
#pragma unroll
        for (int mi = 0; mi < 4; mi++)
#pragma unroll
            for (int ni = 0; ni < 4; ni++)
                acc[mi][ni] = __builtin_amdgcn_mfma_f32_16x16x32_bf16(
                    afr[mi], bfr[ni], acc[mi][ni], 0, 0, 0);
    }

#pragma unroll
    for (int ni = 0; ni < 4; ni++) {
        int col = nbase + nq + ni * 16 + l16;
        if (col >= N) continue;
        float bv = bias ? bias[col] : 0.f;
#pragma unroll
        for (int mi = 0; mi < 4; mi++)
#pragma unroll
            for (int r = 0; r < 4; r++) {
                int row = mbase + mq + mi * 16 + quad * 4 + r;
                if (row >= M) continue;
                float v = acc[mi][ni][r] + bv;
                if (OUTBF) Cb[(size_t)row * ldc + col] = (bf16_t)v;
                else       Cf[(size_t)row * ldc + col] = v;
            }
    }
}

// =======================================================================
// Per-step GRU recurrence (no grid sync; per-row local). One launch carries
// TWO independent layer-steps (L0 step t, L1 step t-4) via blockIdx.y halves.
// Wh slice (96x256, XOR-swizzled) staged once; h tile staged per k-step via
// global_load_lds into chunk-major LDS. gh = h_prev @ Wh^T, gate epilogue.
// =======================================================================
struct RecLay {
    const bf16_t* Gi;      // [NT][768] bf16 (b_ih fused)
    const bf16_t* Wh;      // [768][256]
    const float*  bhh;
    const bf16_t* hprev;   // [NT][256] bf16
    bf16_t*       hout;    // [NT][256] bf16
    float*        hf;      // [NT][256] f32 master
};

__global__ __launch_bounds__(256) void gru_rec_step(RecLay A0, RecLay A1)
{
    const bool second = (blockIdx.y >= YB_);
    const RecLay L = second ? A1 : A0;
    const int byr = second ? (int)blockIdx.y - YB_ : (int)blockIdx.y;

    __shared__ bf16_t Whs[96 * 256];
    __shared__ __align__(16) bf16_t As[512 * 8];
    const int tid  = (int)threadIdx.x;
    const int wave = tid >> 6, lane = tid & 63;
    const int quad = lane >> 4, l16 = lane & 15;
    const int rw = wave & 1, cw = wave >> 1;
    const int bm = byr * 128;
    const int bn = blockIdx.x * 32;

    // stage Wh slice once (row l = gate*32 + j  <->  Wh row gate*256+bn+j)
    for (int u = tid; u < 96 * 32; u += 256) {
        int l = u >> 5, seg = u & 31;
        int grow = (l >> 5) * H_ + bn + (l & 31);
        bf16x8 v = *(const bf16x8*)(L.Wh + (size_t)grow * H_ + seg * 8);
        *(bf16x8*)(Whs + l * H_ + ((seg ^ (l & 7)) * 8)) = v;
    }

    const bf16_t* hgp[2];
#pragma unroll
    for (int j = 0; j < 2; j++) {
        int i = wave * 128 + j * 64 + lane;
        int c = i >> 7, row = i & 127;
        int rg = bm + row; if (rg >= NT_) rg = NT_ - 1;
        hgp[j] = L.hprev + (size_t)rg * H_ + c * 8;
    }
    bf16_t* lsl0 = As + (size_t)(wave * 128) * 8;
    bf16_t* lsl1 = As + (size_t)(wave * 128 + 64) * 8;

    const int col = bn + cw * 16 + l16;
    const float bhr = L.bhh[col], bhz = L.bhh[H_ + col], bhn = L.bhh[2 * H_ + col];

    f32x4 acc[4][3];
#pragma unroll
    for (int mi = 0; mi < 4; mi++)
#pragma unroll
        for (int g = 0; g < 3; g++) acc[mi][g] = (f32x4){0.f, 0.f, 0.f, 0.f};

    for (int k0 = 0; k0 < H_; k0 += 32) {
        __syncthreads();
        gll16(hgp[0] + k0, lsl0);
        gll16(hgp[1] + k0, lsl1);
        __syncthreads();
        bf16x8 bfr[3], afr[4];
#pragma unroll
        for (int g = 0; g < 3; g++) {
            int l = g * 32 + cw * 16 + l16;
            int sf = (k0 >> 3) + quad;
            bfr[g] = *(const bf16x8*)(Whs + l * H_ + ((sf ^ (l & 7)) * 8));
        }
#pragma unroll
        for (int mi = 0; mi < 4; mi++)
            afr[mi] = *(const bf16x8*)(As + (size_t)(quad * 128 + rw * 64 + mi * 16 + l16) * 8);
#pragma unroll
        for (int mi = 0; mi < 4; mi++)
#pragma unroll
            for (int g = 0; g < 3; g++)
                acc[mi][g] = __builtin_amdgcn_mfma_f32_16x16x32_bf16(
                    afr[mi], bfr[g], acc[mi][g], 0, 0, 0);
    }

#pragma unroll
    for (int mi = 0; mi < 4; mi++)
#pragma unroll
        for (int r = 0; r < 4; r++) {
            int m = bm + rw * 64 + mi * 16 + quad * 4 + r;
            if (m >= NT_) continue;
            const bf16_t* gim = L.Gi + (size_t)m * (3 * H_);
            float ir = (float)gim[col];
            float iz = (float)gim[H_ + col];
            float in_ = (float)gim[2 * H_ + col];
            float hr = acc[mi][0][r] + bhr;
            float hz = acc[mi][1][r] + bhz;
            float hn = acc[mi][2][r] + bhn;
            float rg = 1.f / (1.f + expf(-(ir + hr)));
            float zg = 1.f / (1.f + expf(-(iz + hz)));
            float ng = tanhf(in_ + rg * hn);
            size_t o2 = (size_t)m * H_ + col;
            float hnew = (1.f - zg) * ng + zg * L.hf[o2];
            L.hf[o2] = hnew;
            L.hout[o2] = (bf16_t)hnew;
        }
}

// ---------------- prep: all f32->bf16 conversions in one launch ----------------
struct SegD { const float* src; bf16_t* dst; int rows, cin, cout, transp; };
struct PrepArgs { SegD seg[11]; long long base[12]; int nseg; long long total; };

__global__ void prep_kern(PrepArgs pa)
{
    long long stride = (long long)gridDim.x * blockDim.x;
    for (long long i = (long long)blockIdx.x * blockDim.x + threadIdx.x;
         i < pa.total; i += stride) {
        int k = 0;
        while (k + 1 < pa.nseg && i >= pa.base[k + 1]) k++;
        long long local = i - pa.base[k];
        SegD sg = pa.seg[k];
        int r = (int)(local / sg.cout);
        int c = (int)(local - (long long)r * sg.cout);
        float v;
        if (sg.transp) v = sg.src[(size_t)c * sg.rows + r];
        else           v = (c < sg.cin) ? sg.src[(size_t)r * sg.cin + c] : 0.f;
        sg.dst[local] = (bf16_t)v;
    }
}

__global__ void misc_init(int* __restrict__ deg, int* __restrict__ dcnt,
                          float* __restrict__ loss2, float* __restrict__ b_ml,
                          const float* __restrict__ b_mu, const float* __restrict__ b_lv)
{
    int i = blockIdx.x * blockDim.x + threadIdx.x;
    if (i < N_) { deg[i] = 0; dcnt[i] = 0; }
    if (i < 2 * Z_) b_ml[i] = (i < Z_) ? b_mu[i] : b_lv[i - Z_];
    if (i < 2) loss2[i] = 0.f;
}

__global__ void init_h(const float* __restrict__ h0in, float* __restrict__ h0f,
                       float* __restrict__ h1f, bf16_t* __restrict__ h0b,
                       bf16_t* __restrict__ h1b)
{
    int i = blockIdx.x * blockDim.x + threadIdx.x;
    if (i >= NT_ * H_) return;
    float a = h0in[i], b = h0in[NT_ * H_ + i];
    h0f[i] = a; h1f[i] = b;
    h0b[i] = (bf16_t)a; h1b[i] = (bf16_t)b;
}

// ---------------- CSR build (by dst, self-loops appended) ----------------
__device__ __forceinline__ void edge_sd(const int* __restrict__ ei, int e, int& s, int& d)
{
    if (e < E_) { s = ei[e]; d = ei[E_ + e]; }
    else        { s = d = e - E_; }
}

__global__ void csr_hist(const int* __restrict__ ei, int* __restrict__ deg)
{
    int e = blockIdx.x * blockDim.x + threadIdx.x;
    if (e >= E2_) return;
    int s, d; edge_sd(ei, e, s, d);
    atomicAdd(deg + d, 1);
}

__global__ void csr_scan(const int* __restrict__ deg, int* __restrict__ rowptr)
{
    __shared__ int buf[256];
    __shared__ int carry;
    int tid = (int)threadIdx.x;
    if (tid == 0) { carry = 0; rowptr[0] = 0; }
    __syncthreads();
    for (int c0 = 0; c0 < N_; c0 += 256) {
        int i = c0 + tid;
        buf[tid] = (i < N_) ? deg[i] : 0;
        __syncthreads();
        for (int off = 1; off < 256; off <<= 1) {
            int t = (tid >= off) ? buf[tid - off] : 0;
            __syncthreads();
            buf[tid] += t;
            __syncthreads();
        }
        if (i < N_) rowptr[i + 1] = carry + buf[tid];
        __syncthreads();
        if (tid == 255) carry += buf[255];
        __syncthreads();
    }
}

__global__ void csr_scatter(const int* __restrict__ ei, const int* __restrict__ rowptr,
                            int* __restrict__ dcnt, int* __restrict__ csrc)
{
    int e = blockIdx.x * blockDim.x + threadIdx.x;
    if (e >= E2_) return;
    int s, d; edge_sd(ei, e, s, d);
    int pos = rowptr[d] + atomicAdd(dcnt + d, 1);
    csrc[pos] = s;
}

// ---------------- VAE ----------------
__global__ void vae_z_kl(const float* __restrict__ ml, const float* __restrict__ eps,
                         bf16_t* __restrict__ z_out, float* __restrict__ kl_out)
{
    int idx = blockIdx.x * blockDim.x + threadIdx.x;
    float t = 0.f;
    if (idx < NU_ * Z_) {
        int row = idx >> 8, c = idx & 255;
        float m = ml[(size_t)row * 512 + c];
        float l = ml[(size_t)row * 512 + 256 + c];
        float el = expf(l);
        z_out[idx] = (bf16_t)(m + expf(0.5f * l) * eps[idx]);
        t = -0.5f * (1.f + l - m * m - el);
    }
    __shared__ float red[256];
    red[threadIdx.x] = t;
    __syncthreads();
    for (int s = 128; s > 0; s >>= 1) {
        if ((int)threadIdx.x < s) red[threadIdx.x] += red[threadIdx.x + s];
        __syncthreads();
    }
    if (threadIdx.x == 0) atomicAdd(kl_out, red[0] * (1.f / NU_));
}

__global__ void rec_loss_kern(const float* __restrict__ rec, const float* __restrict__ uf,
                              float* __restrict__ loss_out)
{
    int idx = blockIdx.x * blockDim.x + threadIdx.x;
    float t = 0.f;
    if (idx < NU_ * F_) {
        float d = rec[idx] - uf[idx];
        t = d * d;
    }
    __shared__ float red[256];
    red[threadIdx.x] = t;
    __syncthreads();
    for (int s = 128; s > 0; s >>= 1) {
        if ((int)threadIdx.x < s) red[threadIdx.x] += red[threadIdx.x + s];
        __syncthreads();
    }
    if (threadIdx.x == 0) atomicAdd(loss_out, red[0] * (1.f / (NU_ * F_)));
}

// ---------------- assemble x_in = [hn[:B], z, hn[B:]] (bf16) ----------------
__global__ void assemble_xin(const float* __restrict__ h1, bf16_t* __restrict__ x_in)
{
    int idx = blockIdx.x * blockDim.x + threadIdx.x;
    if (idx >= NT_ * H_) return;
    int row = idx >> 8, col = idx & 255;
    int dst = (row < B_) ? row : (row + NU_);
    x_in[(size_t)dst * H_ + col] = (bf16_t)h1[idx];
}

// ---------------- GAT ----------------
// attn coefs, bf16 input (layer 1)
__global__ void gat_attn_coef_bf(const bf16_t* __restrict__ xp,
                                 const float* __restrict__ a_src,
                                 const float* __restrict__ a_dst,
                                 float* __restrict__ asn, float* __restrict__ adn,
                                 int heads, int C)
{
    int i = blockIdx.x * blockDim.x + threadIdx.x;
    if (i >= N_ * heads) return;
    int node = i / heads, h = i - node * heads;
    const bf16_t* x = xp + (size_t)(node * heads + h) * C;
    float s = 0.f, d = 0.f;
    for (int c = 0; c < C; c++) {
        float v = (float)x[c];
        s += v * a_src[h * C + c];
        d += v * a_dst[h * C + c];
    }
    asn[i] = s;
    adn[i] = d;
}

// attn coefs, f32 input (layer 2)
__global__ void gat_attn_coef(const float* __restrict__ xp, const float* __restrict__ a_src,
                              const float* __restrict__ a_dst, float* __restrict__ asn,
                              float* __restrict__ adn, int heads, int C)
{
    int i = blockIdx.x * blockDim.x + threadIdx.x;
    if (i >= N_ * heads) return;
    int node = i / heads, h = i - node * heads;
    const float* x = xp + (size_t)(node * heads + h) * C;
    float s = 0.f, d = 0.f;
    for (int c = 0; c < C; c++) {
        float v = x[c];
        s += v * a_src[h * C + c];
        d += v * a_dst[h * C + c];
    }
    asn[i] = s;
    adn[i] = d;
}

// fused edge-softmax + aggregate, layer 1: BLOCK per dst, all 8 heads.
// thread tid covers channels tid and tid+256 (heads tid>>6 and 4+(tid>>6));
// per edge the block reads the full 1KB bf16 xp row coalesced.
__global__ __launch_bounds__(256) void gat_agg1(
    const int* __restrict__ rowptr, const int* __restrict__ csrc,
    const float* __restrict__ asn, const float* __restrict__ adn,
    const bf16_t* __restrict__ xp, const float* __restrict__ bias,
    bf16_t* __restrict__ x1out)
{
    int d = blockIdx.x;
    int tid = (int)threadIdx.x;
    int beg = rowptr[d], end = rowptr[d + 1];
    int h0 = tid >> 6, h1 = h0 + 4;
    float ad0 = adn[d * 8 + h0], ad1 = adn[d * 8 + h1];
    float mx0 = -1e30f, mx1 = -1e30f;
    for (int e = beg; e < end; e++) {
        int s = csrc[e];
        float l0 = asn[s * 8 + h0] + ad0; l0 = (l0 > 0.f) ? l0 : 0.2f * l0;
        float l1 = asn[s * 8 + h1] + ad1; l1 = (l1 > 0.f) ? l1 : 0.2f * l1;
        mx0 = fmaxf(mx0, l0); mx1 = fmaxf(mx1, l1);
    }
    float den0 = 0.f, den1 = 0.f, acc0 = 0.f, acc1 = 0.f;
    for (int e = beg; e < end; e++) {
        int s = csrc[e];
        float l0 = asn[s * 8 + h0] + ad0; l0 = (l0 > 0.f) ? l0 : 0.2f * l0;
        float l1 = asn[s * 8 + h1] + ad1; l1 = (l1 > 0.f) ? l1 : 0.2f * l1;
        float p0 = expf(l0 - mx0), p1 = expf(l1 - mx1);
        den0 += p0; den1 += p1;
        acc0 += p0 * (float)xp[(size_t)s * 512 + tid];
        acc1 += p1 * (float)xp[(size_t)s * 512 + 256 + tid];
    }
    x1out[(size_t)d * 512 + tid]       = (bf16_t)(bias[tid] + acc0 / den0);
    x1out[(size_t)d * 512 + 256 + tid] = (bf16_t)(bias[256 + tid] + acc1 / den1);
}

// fused edge-softmax + aggregate, layer 2 (1 head x 100ch): wave per dst
__global__ __launch_bounds__(256) void gat_agg2(
    const int* __restrict__ rowptr, const int* __restrict__ csrc,
    const float* __restrict__ asn, const float* __restrict__ adn,
    const float* __restrict__ xp, const float* __restrict__ bias,
    float* __restrict__ outp)
{
    int d = blockIdx.x * 4 + ((int)threadIdx.x >> 6);
    if (d >= N_) return;
    int lane = (int)threadIdx.x & 63;
    int beg = rowptr[d], end = rowptr[d + 1];
    float adnd = adn[d];
    float mx = -1e30f;
    for (int e = beg; e < end; e++) {
        float l = asn[csrc[e]] + adnd;
        l = (l > 0.f) ? l : 0.2f * l;
        mx = fmaxf(mx, l);
    }
    float den = 0.f, acc0 = 0.f, acc1 = 0.f;
    for (int e = beg; e < end; e++) {
        int s = csrc[e];
        float l = asn[s] + adnd;
        l = (l > 0.f) ? l : 0.2f * l;
        float p = expf(l - mx);
        den += p;
        acc0 += p * xp[(size_t)s * H2_ + lane];
        if (lane < H2_ - 64) acc1 += p * xp[(size_t)s * H2_ + 64 + lane];
    }
    outp[(size_t)d * H2_ + lane] = bias[lane] + acc0 / den;
    if (lane < H2_ - 64)
        outp[(size_t)d * H2_ + 64 + lane] = bias[64 + lane] + acc1 / den;
}

// ---------------- launcher ----------------
extern "C" void kernel_launch(void* const* d_in, const int* in_sizes, int n_in,
                              void* d_out, int out_size, void* d_ws, size_t ws_size,
                              hipStream_t stream)
{
    const float* user_feats = (const float*)d_in[1];
    const int*   gnf        = (const int*)d_in[2];
    const int*   ei         = (const int*)d_in[3];
    const float* temb       = (const float*)d_in[4];
    const float* w_ih0      = (const float*)d_in[5];
    const float* w_hh0      = (const float*)d_in[6];
    const float* b_ih0      = (const float*)d_in[7];
    const float* b_hh0      = (const float*)d_in[8];
    const float* w_ih1      = (const float*)d_in[9];
    const float* w_hh1      = (const float*)d_in[10];
    const float* b_ih1      = (const float*)d_in[11];
    const float* b_hh1      = (const float*)d_in[12];
    const float* h0in       = (const float*)d_in[13];
    const float* w_mu       = (const float*)d_in[14];
    const float* b_mu       = (const float*)d_in[15];
    const float* w_lv       = (const float*)d_in[16];
    const float* b_lv       = (const float*)d_in[17];
    const float* w_dec      = (const float*)d_in[18];
    const float* b_dec      = (const float*)d_in[19];
    const float* veps       = (const float*)d_in[20];
    const float* w1         = (const float*)d_in[21];
    const float* a_src1     = (const float*)d_in[22];
    const float* a_dst1     = (const float*)d_in[23];
    const float* b1         = (const float*)d_in[24];
    const float* w2         = (const float*)d_in[25];
    const float* a_src2     = (const float*)d_in[26];
    const float* a_dst2     = (const float*)d_in[27];
    const float* b2         = (const float*)d_in[28];
    float* out = (float*)d_out;

    // ---- workspace (byte offsets) ----
    char* wsb = (char*)d_ws;
    bf16_t* temb_bf = (bf16_t*)(wsb + 0);                 // 19.2 MB
    bf16_t* Gi0     = (bf16_t*)(wsb + 19200000);          // 36.86 MB
    bf16_t* Gi1     = (bf16_t*)(wsb + 56064000);          // 36.86 MB (ends 92,928,000)
    //   VAE aliases (before GRU, inside Gi1):
    float*  mlbuf   = (float*)(wsb + 56064000);           // 8.19 MB
    float*  recb    = (float*)(wsb + 64256000);           // 8.19 MB
    //   GAT aliases (after GRU, inside temb/Gi0):
    bf16_t* xp1b    = (bf16_t*)(wsb + 0);                 // 10.24 MB (bf16)
    bf16_t* x1b     = (bf16_t*)(wsb + 20480000);          // 10.24 MB
    float*  xp2     = (float*)(wsb + 30720000);           // 4.0 MB
    // persistent weights / state
    bf16_t* wih0_bf = (bf16_t*)(wsb + 92928000);
    bf16_t* whh0_bf = (bf16_t*)(wsb + 93419520);
    bf16_t* wih1_bf = (bf16_t*)(wsb + 93812736);
    bf16_t* whh1_bf = (bf16_t*)(wsb + 94205952);
    bf16_t* wml_bf  = (bf16_t*)(wsb + 94599168);
    bf16_t* wdec_bf = (bf16_t*)(wsb + 95123456);
    bf16_t* w1t_bf  = (bf16_t*)(wsb + 95385600);
    bf16_t* w2t_bf  = (bf16_t*)(wsb + 95648000);
    float*  b_ml    = (float*)(wsb + 95750400);
    bf16_t* ufeats_bf = (bf16_t*)(wsb + 95752448);
    bf16_t* out0    = (bf16_t*)(wsb + 99848448);          // 4 slots x 3,072,000
    float*  h0f     = (float*)(wsb + 112136448);
    float*  h1f     = (float*)(wsb + 118280448);
    bf16_t* h0b_init = (bf16_t*)(wsb + 124424448);
    bf16_t* h1init  = (bf16_t*)(wsb + 127496448);
    bf16_t* h1sA    = (bf16_t*)(wsb + 130568448);
    bf16_t* h1sB    = (bf16_t*)(wsb + 133640448);
    bf16_t* xin_bf  = (bf16_t*)(wsb + 136712448);
    int*    deg     = (int*)(wsb + 141832448);
    int*    dcnt    = (int*)(wsb + 141872448);
    int*    rowptr  = (int*)(wsb + 141912448);
    int*    csrc    = (int*)(wsb + 141952512);
    float*  asn1    = (float*)(wsb + 142312512);
    float*  adn1    = (float*)(wsb + 142632512);
    float*  asn2    = (float*)(wsb + 142952512);
    float*  adn2    = (float*)(wsb + 142992512);

    const int TB = 256;
    auto blocks = [](int n) { return (n + 255) / 256; };
    auto ggrid = [](int M, int N) { return dim3((N + 127) / 128, (M + 127) / 128); };

    // ---- prep ----
    PrepArgs pa;
    auto seg = [&](int k, const float* s, bf16_t* dst, int rows, int cin, int cout, int tr) {
        pa.seg[k] = SegD{s, dst, rows, cin, cout, tr};
    };
    seg(0, temb, temb_bf, V_, D_, DP_, 0);
    seg(1, w_ih0, wih0_bf, 3 * H_, D_, DP_, 0);
    seg(2, w_hh0, whh0_bf, 3 * H_, H_, H_, 0);
    seg(3, w_ih1, wih1_bf, 3 * H_, H_, H_, 0);
    seg(4, w_hh1, whh1_bf, 3 * H_, H_, H_, 0);
    seg(5, w_mu, wml_bf, Z_, F_, F_, 0);
    seg(6, w_lv, wml_bf + (size_t)Z_ * F_, Z_, F_, F_, 0);
    seg(7, w_dec, wdec_bf, F_, Z_, Z_, 0);
    seg(8, user_feats, ufeats_bf, NU_, F_, F_, 0);
    seg(9, w1, w1t_bf, HEADS_ * H1_, 0, H_, 1);
    seg(10, w2, w2t_bf, H2_, 0, HEADS_ * H1_, 1);
    pa.nseg = 11;
    long long acc = 0;
    for (int k = 0; k < 11; k++) {
        pa.base[k] = acc;
        acc += (long long)pa.seg[k].rows * pa.seg[k].cout;
    }
    pa.base[11] = acc;
    pa.total = acc;
    hipLaunchKernelGGL(prep_kern, dim3(6144), dim3(TB), 0, stream, pa);

    hipLaunchKernelGGL(misc_init, dim3(blocks(N_)), dim3(TB), 0, stream,
                       deg, dcnt, out + N_ * H2_, b_ml, b_mu, b_lv);
    hipLaunchKernelGGL(init_h, dim3(blocks(NT_ * H_)), dim3(TB), 0, stream,
                       h0in, h0f, h1f, h0b_init, h1init);

    // ---- CSR build ----
    hipLaunchKernelGGL(csr_hist, dim3(blocks(E2_)), dim3(TB), 0, stream, ei, deg);
    hipLaunchKernelGGL(csr_scan, dim3(1), dim3(TB), 0, stream, deg, rowptr);
    hipLaunchKernelGGL(csr_scatter, dim3(blocks(E2_)), dim3(TB), 0, stream,
                       ei, rowptr, dcnt, csrc);

    // ---- VAE ----
    hipLaunchKernelGGL((mfma_gemm<0, false>), ggrid(NU_, 2 * Z_), dim3(TB), 0, stream,
                       ufeats_bf, wml_bf, b_ml, mlbuf, (bf16_t*)nullptr,
                       NU_, 2 * Z_, F_, 2 * Z_, (const int*)nullptr, 0);
    bf16_t* z_bf = xin_bf + (size_t)B_ * H_;
    hipLaunchKernelGGL(vae_z_kl, dim3(blocks(NU_ * Z_)), dim3(TB), 0, stream,
                       mlbuf, veps, z_bf, out + N_ * H2_);
    hipLaunchKernelGGL((mfma_gemm<0, false>), ggrid(NU_, F_), dim3(TB), 0, stream,
                       z_bf, wdec_bf, b_dec, recb, (bf16_t*)nullptr,
                       NU_, F_, Z_, F_, (const int*)nullptr, 0);
    hipLaunchKernelGGL(rec_loss_kern, dim3(blocks(NU_ * F_)), dim3(TB), 0, stream,
                       recb, user_feats, out + N_ * H2_ + 1);

    // ---- 2-layer GRU: chunked gi GEMMs + paired per-step recurrence ----
    const int MC = TCH_ * NT_;
    auto recL0 = [&](int c, int s) -> RecLay {
        RecLay L;
        L.Gi = Gi0 + (size_t)s * NT_ * 3 * H_;
        L.Wh = whh0_bf; L.bhh = b_hh0;
        L.hprev = (c == 0 && s == 0) ? h0b_init
                : (s == 0) ? out0 + (size_t)3 * NT_ * H_
                           : out0 + (size_t)(s - 1) * NT_ * H_;
        L.hout = out0 + (size_t)s * NT_ * H_;
        L.hf = h0f;
        return L;
    };
    auto recL1 = [&](int c, int s) -> RecLay {
        int t = 4 * c + s;
        RecLay L;
        L.Gi = Gi1 + (size_t)s * NT_ * 3 * H_;
        L.Wh = whh1_bf; L.bhh = b_hh1;
        L.hprev = (t == 0) ? h1init : (((t - 1) & 1) ? h1sB : h1sA);
        L.hout = (t & 1) ? h1sB : h1sA;
        L.hf = h1f;
        return L;
    };

    // chunk 0: L0 only
    hipLaunchKernelGGL((mfma_gemm<1, true>), ggrid(MC, 3 * H_), dim3(TB), 0, stream,
                       temb_bf, wih0_bf, b_ih0, (float*)nullptr, Gi0,
                       MC, 3 * H_, DP_, 3 * H_, gnf, 0);
    for (int s = 0; s < TCH_; s++) {
        RecLay L = recL0(0, s);
        hipLaunchKernelGGL(gru_rec_step, dim3(H_ / 32, YB_), dim3(TB), 0, stream, L, L);
    }
    // chunks 1..5: paired (L0 chunk c, L1 chunk c-1)
    for (int c = 1; c < T_ / TCH_; c++) {
        hipLaunchKernelGGL((mfma_gemm<0, true>), ggrid(MC, 3 * H_), dim3(TB), 0, stream,
                           out0, wih1_bf, b_ih1, (float*)nullptr, Gi1,
                           MC, 3 * H_, H_, 3 * H_, (const int*)nullptr, 0);
        hipLaunchKernelGGL((mfma_gemm<1, true>), ggrid(MC, 3 * H_), dim3(TB), 0, stream,
                           temb_bf, wih0_bf, b_ih0, (float*)nullptr, Gi0,
                           MC, 3 * H_, DP_, 3 * H_, gnf, 4 * c);
        for (int s = 0; s < TCH_; s++) {
            RecLay L0 = recL0(c, s), L1 = recL1(c - 1, s);
            hipLaunchKernelGGL(gru_rec_step, dim3(H_ / 32, 2 * YB_), dim3(TB), 0, stream,
                               L0, L1);
        }
    }
    // final: L1 chunk 5
    hipLaunchKernelGGL((mfma_gemm<0, true>), ggrid(MC, 3 * H_), dim3(TB), 0, stream,
                       out0, wih1_bf, b_ih1, (float*)nullptr, Gi1,
                       MC, 3 * H_, H_, 3 * H_, (const int*)nullptr, 0);
    for (int s = 0; s < TCH_; s++) {
        RecLay L = recL1(T_ / TCH_ - 1, s);
        hipLaunchKernelGGL(gru_rec_step, dim3(H_ / 32, YB_), dim3(TB), 0, stream, L, L);
    }

    // ---- assemble x_in ----
    hipLaunchKernelGGL(assemble_xin, dim3(blocks(NT_ * H_)), dim3(TB), 0, stream,
                       h1f, xin_bf);

    // ---- GAT layer 1 (xp1 in bf16) ----
    hipLaunchKernelGGL((mfma_gemm<0, true>), ggrid(N_, HEADS_ * H1_), dim3(TB), 0, stream,
                       xin_bf, w1t_bf, (const float*)nullptr, (float*)nullptr, xp1b,
                       N_, HEADS_ * H1_, H_, HEADS_ * H1_, (const int*)nullptr, 0);
    hipLaunchKernelGGL(gat_attn_coef_bf, dim3(blocks(N_ * HEADS_)), dim3(TB), 0, stream,
                       xp1b, a_src1, a_dst1, asn1, adn1, HEADS_, H1_);
    hipLaunchKernelGGL(gat_agg1, dim3(N_), dim3(TB), 0, stream,
                       rowptr, csrc, asn1, adn1, xp1b, b1, x1b);

    // ---- GAT layer 2 ----
    hipLaunchKernelGGL((mfma_gemm<0, false>), ggrid(N_, H2_), dim3(TB), 0, stream,
                       x1b, w2t_bf, (const float*)nullptr, xp2, (bf16_t*)nullptr,
                       N_, H2_, HEADS_ * H1_, H2_, (const int*)nullptr, 0);
    hipLaunchKernelGGL(gat_attn_coef, dim3(blocks(N_)), dim3(TB), 0, stream,
                       xp2, a_src2, a_dst2, asn2, adn2, 1, H2_);
    hipLaunchKernelGGL(gat_agg2, dim3((N_ + 3) / 4), dim3(TB), 0, stream,
                       rowptr, csrc, asn2, adn2, xp2, b2, out);

    (void)in_sizes; (void)n_in; (void)out_size; (void)ws_size;
}

// Round 7
// 2149.386 us; speedup vs baseline: 1.0590x; 1.0590x over previous
//
#include <hip/hip_runtime.h>

// ---- problem dims (fixed by reference) ----
#define V_ 30000
#define D_ 300
#define DP_ 320
#define T_ 24
#define H_ 256
#define NT_ 6000
#define NU_ 4000
#define N_ 10000
#define F_ 512
#define Z_ 256
#define E_ 80000
#define B_ 2000
#define H1_ 64
#define H2_ 100
#define HEADS_ 8
#define E2_ (E_ + N_)
#define TCH_ 4
#define YB_ 47          // row-blocks per layer in rec grid (47*128 >= 6000)

typedef __bf16 bf16_t;
typedef bf16_t bf16x8 __attribute__((ext_vector_type(8)));
typedef float  f32x4  __attribute__((ext_vector_type(4)));

// async global->LDS, 16B per lane; lds dest = base + lane*16 (wave-uniform base)
__device__ __forceinline__ void gll16(const bf16_t* g, bf16_t* l)
{
    __builtin_amdgcn_global_load_lds(
        (const __attribute__((address_space(1))) void*)g,
        (__attribute__((address_space(3))) void*)l, 16, 0, 0);
}

// =======================================================================
// 128x128 MFMA GEMM, global_load_lds staging: C = A[M,K] @ B[N,K]^T (+bias)
// LDS chunk-major layout: slot i = c*128+row holds A[row][k0+c*8 .. +8).
// GM=1: A rows gathered (embedding lookup).
// =======================================================================
template<int GM, bool OUTBF>
__global__ __launch_bounds__(256) void mfma_gemm(
    const bf16_t* __restrict__ A, const bf16_t* __restrict__ B,
    const float* __restrict__ bias, float* __restrict__ Cf,
    bf16_t* __restrict__ Cb, int M, int N, int K, int ldc,
    const int* __restrict__ gtok, int t0)
{
    __shared__ __align__(16) bf16_t As[512 * 8];
    __shared__ __align__(16) bf16_t Bs[512 * 8];
    const int tid  = (int)threadIdx.x;
    const int wave = tid >> 6, lane = tid & 63;
    const int quad = lane >> 4, l16 = lane & 15;
    const int mq = (wave & 1) * 64, nq = (wave >> 1) * 64;
    const int mbase = blockIdx.y * 128, nbase = blockIdx.x * 128;

    const bf16_t* agp[2];
    const bf16_t* bgp[2];
#pragma unroll
    for (int j = 0; j < 2; j++) {
        int i = wave * 128 + j * 64 + lane;
        int c = i >> 7, row = i & 127;
        int r = mbase + row; if (r >= M) r = M - 1;
        int src = (GM == 1) ? gtok[(r % NT_) * T_ + t0 + (r / NT_)] : r;
        agp[j] = A + (size_t)src * K + c * 8;
        int rb = nbase + row; if (rb >= N) rb = N - 1;
        bgp[j] = B + (size_t)rb * K + c * 8;
    }
    bf16_t* asl0 = As + (size_t)(wave * 128) * 8;
    bf16_t* asl1 = As + (size_t)(wave * 128 + 64) * 8;
    bf16_t* bsl0 = Bs + (size_t)(wave * 128) * 8;
    bf16_t* bsl1 = Bs + (size_t)(wave * 128 + 64) * 8;

    f32x4 acc[4][4];
#pragma unroll
    for (int mi = 0; mi < 4; mi++)
#pragma unroll
        for (int ni = 0; ni < 4; ni++) acc[mi][ni] = (f32x4){0.f, 0.f, 0.f, 0.f};

    for (int k0 = 0; k0 < K; k0 += 32) {
        __syncthreads();
        gll16(agp[0] + k0, asl0);
        gll16(agp[1] + k0, asl1);
        gll16(bgp[0] + k0, bsl0);
        gll16(bgp[1] + k0, bsl1);
        __syncthreads();
        bf16x8 afr[4], bfr[4];
#pragma unroll
        for (int mi = 0; mi < 4; mi++)
            afr[mi] = *(const bf16x8*)(As + (size_t)(quad * 128 + mq + mi * 16 + l16) * 8);
#pragma unroll
        for (int ni = 0; ni < 4; ni++)
            bfr[ni] = *(const bf16x8*)(Bs + (size_t)(quad * 128 + nq + ni * 16 + l16) * 8);
#pragma unroll
        for (int mi = 0; mi < 4; mi++)
#pragma unroll
            for (int ni = 0; ni < 4; ni++)
                acc[mi][ni] = __builtin_amdgcn_mfma_f32_16x16x32_bf16(
                    afr[mi], bfr[ni], acc[mi][ni], 0, 0, 0);
    }

#pragma unroll
    for (int ni = 0; ni < 4; ni++) {
        int col = nbase + nq + ni * 16 + l16;
        if (col >= N) continue;
        float bv = bias ? bias[col] : 0.f;
#pragma unroll
        for (int mi = 0; mi < 4; mi++)
#pragma unroll
            for (int r = 0; r < 4; r++) {
                int row = mbase + mq + mi * 16 + quad * 4 + r;
                if (row >= M) continue;
                float v = acc[mi][ni][r] + bv;
                if (OUTBF) Cb[(size_t)row * ldc + col] = (bf16_t)v;
                else       Cf[(size_t)row * ldc + col] = v;
            }
    }
}

// =======================================================================
// Per-step GRU recurrence. One launch carries TWO independent layer-steps
// (L0 step t, L1 step t-4) via blockIdx.y halves. Block = 128 rows x 32 cols.
// Wh B-fragments held in VGPRs (3 gates x 8 k-steps x bf16x8 = 96 VGPR),
// loaded once from global (L2-hot). Only h-tile staged in LDS (8KB) via
// global_load_lds per k-step. gh = h_prev @ Wh^T by MFMA, gate epilogue.
// =======================================================================
struct RecLay {
    const bf16_t* Gi;      // [NT][768] bf16 (b_ih fused)
    const bf16_t* Wh;      // [768][256]
    const float*  bhh;
    const bf16_t* hprev;   // [NT][256] bf16
    bf16_t*       hout;    // [NT][256] bf16
    float*        hf;      // [NT][256] f32 master
};

__global__ __launch_bounds__(256) void gru_rec_step(RecLay A0, RecLay A1)
{
    const bool second = (blockIdx.y >= YB_);
    const RecLay L = second ? A1 : A0;
    const int byr = second ? (int)blockIdx.y - YB_ : (int)blockIdx.y;

    __shared__ __align__(16) bf16_t As[512 * 8];
    const int tid  = (int)threadIdx.x;
    const int wave = tid >> 6, lane = tid & 63;
    const int quad = lane >> 4, l16 = lane & 15;
    const int rw = wave & 1, cw = wave >> 1;
    const int bm = byr * 128;
    const int bn = blockIdx.x * 32;
    const int col = bn + cw * 16 + l16;

    // Wh B-fragments into registers: wfr[g][ks] covers k = ks*32 + quad*8 .. +8
    bf16x8 wfr[3][8];
#pragma unroll
    for (int g = 0; g < 3; g++) {
        const bf16_t* wrow = L.Wh + (size_t)(g * H_ + col) * H_ + quad * 8;
#pragma unroll
        for (int ks = 0; ks < 8; ks++)
            wfr[g][ks] = *(const bf16x8*)(wrow + ks * 32);
    }

    const bf16_t* hgp[2];
#pragma unroll
    for (int j = 0; j < 2; j++) {
        int i = wave * 128 + j * 64 + lane;
        int c = i >> 7, row = i & 127;
        int rg = bm + row; if (rg >= NT_) rg = NT_ - 1;
        hgp[j] = L.hprev + (size_t)rg * H_ + c * 8;
    }
    bf16_t* lsl0 = As + (size_t)(wave * 128) * 8;
    bf16_t* lsl1 = As + (size_t)(wave * 128 + 64) * 8;

    const float bhr = L.bhh[col], bhz = L.bhh[H_ + col], bhn = L.bhh[2 * H_ + col];

    f32x4 acc[4][3];
#pragma unroll
    for (int mi = 0; mi < 4; mi++)
#pragma unroll
        for (int g = 0; g < 3; g++) acc[mi][g] = (f32x4){0.f, 0.f, 0.f, 0.f};

#pragma unroll
    for (int ks = 0; ks < 8; ks++) {
        const int k0 = ks * 32;
        __syncthreads();
        gll16(hgp[0] + k0, lsl0);
        gll16(hgp[1] + k0, lsl1);
        __syncthreads();
        bf16x8 afr[4];
#pragma unroll
        for (int mi = 0; mi < 4; mi++)
            afr[mi] = *(const bf16x8*)(As + (size_t)(quad * 128 + rw * 64 + mi * 16 + l16) * 8);
#pragma unroll
        for (int mi = 0; mi < 4; mi++)
#pragma unroll
            for (int g = 0; g < 3; g++)
                acc[mi][g] = __builtin_amdgcn_mfma_f32_16x16x32_bf16(
                    afr[mi], wfr[g][ks], acc[mi][g], 0, 0, 0);
    }

#pragma unroll
    for (int mi = 0; mi < 4; mi++)
#pragma unroll
        for (int r = 0; r < 4; r++) {
            int m = bm + rw * 64 + mi * 16 + quad * 4 + r;
            if (m >= NT_) continue;
            const bf16_t* gim = L.Gi + (size_t)m * (3 * H_);
            float ir = (float)gim[col];
            float iz = (float)gim[H_ + col];
            float in_ = (float)gim[2 * H_ + col];
            float hr = acc[mi][0][r] + bhr;
            float hz = acc[mi][1][r] + bhz;
            float hn = acc[mi][2][r] + bhn;
            float rg = 1.f / (1.f + expf(-(ir + hr)));
            float zg = 1.f / (1.f + expf(-(iz + hz)));
            float ng = tanhf(in_ + rg * hn);
            size_t o2 = (size_t)m * H_ + col;
            float hnew = (1.f - zg) * ng + zg * L.hf[o2];
            L.hf[o2] = hnew;
            L.hout[o2] = (bf16_t)hnew;
        }
}

// ---------------- prep: all f32->bf16 conversions in one launch ----------------
struct SegD { const float* src; bf16_t* dst; int rows, cin, cout, transp; };
struct PrepArgs { SegD seg[11]; long long base[12]; int nseg; long long total; };

__global__ void prep_kern(PrepArgs pa)
{
    long long stride = (long long)gridDim.x * blockDim.x;
    for (long long i = (long long)blockIdx.x * blockDim.x + threadIdx.x;
         i < pa.total; i += stride) {
        int k = 0;
        while (k + 1 < pa.nseg && i >= pa.base[k + 1]) k++;
        long long local = i - pa.base[k];
        SegD sg = pa.seg[k];
        int r = (int)(local / sg.cout);
        int c = (int)(local - (long long)r * sg.cout);
        float v;
        if (sg.transp) v = sg.src[(size_t)c * sg.rows + r];
        else           v = (c < sg.cin) ? sg.src[(size_t)r * sg.cin + c] : 0.f;
        sg.dst[local] = (bf16_t)v;
    }
}

// ---------------- fused init: h states + CSR counters + losses + VAE bias ----
__global__ void init_all(const float* __restrict__ h0in, float* __restrict__ h0f,
                         float* __restrict__ h1f, bf16_t* __restrict__ h0b,
                         bf16_t* __restrict__ h1b,
                         int* __restrict__ deg, int* __restrict__ dcnt,
                         float* __restrict__ loss2, float* __restrict__ b_ml,
                         const float* __restrict__ b_mu, const float* __restrict__ b_lv)
{
    int i = blockIdx.x * blockDim.x + threadIdx.x;
    if (i < NT_ * H_) {
        float a = h0in[i], b = h0in[NT_ * H_ + i];
        h0f[i] = a; h1f[i] = b;
        h0b[i] = (bf16_t)a; h1b[i] = (bf16_t)b;
    }
    if (i < N_) { deg[i] = 0; dcnt[i] = 0; }
    if (i < 2 * Z_) b_ml[i] = (i < Z_) ? b_mu[i] : b_lv[i - Z_];
    if (i < 2) loss2[i] = 0.f;
}

// ---------------- CSR build (by dst, self-loops appended) ----------------
__device__ __forceinline__ void edge_sd(const int* __restrict__ ei, int e, int& s, int& d)
{
    if (e < E_) { s = ei[e]; d = ei[E_ + e]; }
    else        { s = d = e - E_; }
}

__global__ void csr_hist(const int* __restrict__ ei, int* __restrict__ deg)
{
    int e = blockIdx.x * blockDim.x + threadIdx.x;
    if (e >= E2_) return;
    int s, d; edge_sd(ei, e, s, d);
    atomicAdd(deg + d, 1);
}

__global__ void csr_scan(const int* __restrict__ deg, int* __restrict__ rowptr)
{
    __shared__ int buf[256];
    __shared__ int carry;
    int tid = (int)threadIdx.x;
    if (tid == 0) { carry = 0; rowptr[0] = 0; }
    __syncthreads();
    for (int c0 = 0; c0 < N_; c0 += 256) {
        int i = c0 + tid;
        buf[tid] = (i < N_) ? deg[i] : 0;
        __syncthreads();
        for (int off = 1; off < 256; off <<= 1) {
            int t = (tid >= off) ? buf[tid - off] : 0;
            __syncthreads();
            buf[tid] += t;
            __syncthreads();
        }
        if (i < N_) rowptr[i + 1] = carry + buf[tid];
        __syncthreads();
        if (tid == 255) carry += buf[255];
        __syncthreads();
    }
}

__global__ void csr_scatter(const int* __restrict__ ei, const int* __restrict__ rowptr,
                            int* __restrict__ dcnt, int* __restrict__ csrc)
{
    int e = blockIdx.x * blockDim.x + threadIdx.x;
    if (e >= E2_) return;
    int s, d; edge_sd(ei, e, s, d);
    int pos = rowptr[d] + atomicAdd(dcnt + d, 1);
    csrc[pos] = s;
}

// ---------------- VAE (grid-stride: 256 atomics total, not 12000) ----------------
__global__ __launch_bounds__(256) void vae_z_kl(
    const float* __restrict__ ml, const float* __restrict__ eps,
    bf16_t* __restrict__ z_out, float* __restrict__ kl_out)
{
    float t = 0.f;
    int stride = (int)gridDim.x * 256;
    for (int idx = blockIdx.x * 256 + threadIdx.x; idx < NU_ * Z_; idx += stride) {
        int row = idx >> 8, c = idx & 255;
        float m = ml[(size_t)row * 512 + c];
        float l = ml[(size_t)row * 512 + 256 + c];
        float el = expf(l);
        z_out[idx] = (bf16_t)(m + expf(0.5f * l) * eps[idx]);
        t += -0.5f * (1.f + l - m * m - el);
    }
    __shared__ float red[256];
    red[threadIdx.x] = t;
    __syncthreads();
    for (int s = 128; s > 0; s >>= 1) {
        if ((int)threadIdx.x < s) red[threadIdx.x] += red[threadIdx.x + s];
        __syncthreads();
    }
    if (threadIdx.x == 0) atomicAdd(kl_out, red[0] * (1.f / NU_));
}

__global__ __launch_bounds__(256) void rec_loss_kern(
    const float* __restrict__ rec, const float* __restrict__ uf,
    float* __restrict__ loss_out)
{
    float t = 0.f;
    int stride = (int)gridDim.x * 256;
    for (int idx = blockIdx.x * 256 + threadIdx.x; idx < NU_ * F_; idx += stride) {
        float d = rec[idx] - uf[idx];
        t += d * d;
    }
    __shared__ float red[256];
    red[threadIdx.x] = t;
    __syncthreads();
    for (int s = 128; s > 0; s >>= 1) {
        if ((int)threadIdx.x < s) red[threadIdx.x] += red[threadIdx.x + s];
        __syncthreads();
    }
    if (threadIdx.x == 0) atomicAdd(loss_out, red[0] * (1.f / (NU_ * F_)));
}

// ---------------- assemble x_in = [hn[:B], z, hn[B:]] (bf16) ----------------
__global__ void assemble_xin(const float* __restrict__ h1, bf16_t* __restrict__ x_in)
{
    int idx = blockIdx.x * blockDim.x + threadIdx.x;
    if (idx >= NT_ * H_) return;
    int row = idx >> 8, col = idx & 255;
    int dst = (row < B_) ? row : (row + NU_);
    x_in[(size_t)dst * H_ + col] = (bf16_t)h1[idx];
}

// ---------------- GAT ----------------
__global__ void gat_attn_coef_bf(const bf16_t* __restrict__ xp,
                                 const float* __restrict__ a_src,
                                 const float* __restrict__ a_dst,
                                 float* __restrict__ asn, float* __restrict__ adn,
                                 int heads, int C)
{
    int i = blockIdx.x * blockDim.x + threadIdx.x;
    if (i >= N_ * heads) return;
    int node = i / heads, h = i - node * heads;
    const bf16_t* x = xp + (size_t)(node * heads + h) * C;
    float s = 0.f, d = 0.f;
    for (int c = 0; c < C; c++) {
        float v = (float)x[c];
        s += v * a_src[h * C + c];
        d += v * a_dst[h * C + c];
    }
    asn[i] = s;
    adn[i] = d;
}

__global__ void gat_attn_coef(const float* __restrict__ xp, const float* __restrict__ a_src,
                              const float* __restrict__ a_dst, float* __restrict__ asn,
                              float* __restrict__ adn, int heads, int C)
{
    int i = blockIdx.x * blockDim.x + threadIdx.x;
    if (i >= N_ * heads) return;
    int node = i / heads, h = i - node * heads;
    const float* x = xp + (size_t)(node * heads + h) * C;
    float s = 0.f, d = 0.f;
    for (int c = 0; c < C; c++) {
        float v = x[c];
        s += v * a_src[h * C + c];
        d += v * a_dst[h * C + c];
    }
    asn[i] = s;
    adn[i] = d;
}

// fused edge-softmax + aggregate, layer 1: BLOCK per dst, all 8 heads.
__global__ __launch_bounds__(256) void gat_agg1(
    const int* __restrict__ rowptr, const int* __restrict__ csrc,
    const float* __restrict__ asn, const float* __restrict__ adn,
    const bf16_t* __restrict__ xp, const float* __restrict__ bias,
    bf16_t* __restrict__ x1out)
{
    int d = blockIdx.x;
    int tid = (int)threadIdx.x;
    int beg = rowptr[d], end = rowptr[d + 1];
    int h0 = tid >> 6, h1 = h0 + 4;
    float ad0 = adn[d * 8 + h0], ad1 = adn[d * 8 + h1];
    float mx0 = -1e30f, mx1 = -1e30f;
    for (int e = beg; e < end; e++) {
        int s = csrc[e];
        float l0 = asn[s * 8 + h0] + ad0; l0 = (l0 > 0.f) ? l0 : 0.2f * l0;
        float l1 = asn[s * 8 + h1] + ad1; l1 = (l1 > 0.f) ? l1 : 0.2f * l1;
        mx0 = fmaxf(mx0, l0); mx1 = fmaxf(mx1, l1);
    }
    float den0 = 0.f, den1 = 0.f, acc0 = 0.f, acc1 = 0.f;
    for (int e = beg; e < end; e++) {
        int s = csrc[e];
        float l0 = asn[s * 8 + h0] + ad0; l0 = (l0 > 0.f) ? l0 : 0.2f * l0;
        float l1 = asn[s * 8 + h1] + ad1; l1 = (l1 > 0.f) ? l1 : 0.2f * l1;
        float p0 = expf(l0 - mx0), p1 = expf(l1 - mx1);
        den0 += p0; den1 += p1;
        acc0 += p0 * (float)xp[(size_t)s * 512 + tid];
        acc1 += p1 * (float)xp[(size_t)s * 512 + 256 + tid];
    }
    x1out[(size_t)d * 512 + tid]       = (bf16_t)(bias[tid] + acc0 / den0);
    x1out[(size_t)d * 512 + 256 + tid] = (bf16_t)(bias[256 + tid] + acc1 / den1);
}

// fused edge-softmax + aggregate, layer 2 (1 head x 100ch): wave per dst
__global__ __launch_bounds__(256) void gat_agg2(
    const int* __restrict__ rowptr, const int* __restrict__ csrc,
    const float* __restrict__ asn, const float* __restrict__ adn,
    const float* __restrict__ xp, const float* __restrict__ bias,
    float* __restrict__ outp)
{
    int d = blockIdx.x * 4 + ((int)threadIdx.x >> 6);
    if (d >= N_) return;
    int lane = (int)threadIdx.x & 63;
    int beg = rowptr[d], end = rowptr[d + 1];
    float adnd = adn[d];
    float mx = -1e30f;
    for (int e = beg; e < end; e++) {
        float l = asn[csrc[e]] + adnd;
        l = (l > 0.f) ? l : 0.2f * l;
        mx = fmaxf(mx, l);
    }
    float den = 0.f, acc0 = 0.f, acc1 = 0.f;
    for (int e = beg; e < end; e++) {
        int s = csrc[e];
        float l = asn[s] + adnd;
        l = (l > 0.f) ? l : 0.2f * l;
        float p = expf(l - mx);
        den += p;
        acc0 += p * xp[(size_t)s * H2_ + lane];
        if (lane < H2_ - 64) acc1 += p * xp[(size_t)s * H2_ + 64 + lane];
    }
    outp[(size_t)d * H2_ + lane] = bias[lane] + acc0 / den;
    if (lane < H2_ - 64)
        outp[(size_t)d * H2_ + 64 + lane] = bias[64 + lane] + acc1 / den;
}

// ---------------- launcher ----------------
extern "C" void kernel_launch(void* const* d_in, const int* in_sizes, int n_in,
                              void* d_out, int out_size, void* d_ws, size_t ws_size,
                              hipStream_t stream)
{
    const float* user_feats = (const float*)d_in[1];
    const int*   gnf        = (const int*)d_in[2];
    const int*   ei         = (const int*)d_in[3];
    const float* temb       = (const float*)d_in[4];
    const float* w_ih0      = (const float*)d_in[5];
    const float* w_hh0      = (const float*)d_in[6];
    const float* b_ih0      = (const float*)d_in[7];
    const float* b_hh0      = (const float*)d_in[8];
    const float* w_ih1      = (const float*)d_in[9];
    const float* w_hh1      = (const float*)d_in[10];
    const float* b_ih1      = (const float*)d_in[11];
    const float* b_hh1      = (const float*)d_in[12];
    const float* h0in       = (const float*)d_in[13];
    const float* w_mu       = (const float*)d_in[14];
    const float* b_mu       = (const float*)d_in[15];
    const float* w_lv       = (const float*)d_in[16];
    const float* b_lv       = (const float*)d_in[17];
    const float* w_dec      = (const float*)d_in[18];
    const float* b_dec      = (const float*)d_in[19];
    const float* veps       = (const float*)d_in[20];
    const float* w1         = (const float*)d_in[21];
    const float* a_src1     = (const float*)d_in[22];
    const float* a_dst1     = (const float*)d_in[23];
    const float* b1         = (const float*)d_in[24];
    const float* w2         = (const float*)d_in[25];
    const float* a_src2     = (const float*)d_in[26];
    const float* a_dst2     = (const float*)d_in[27];
    const float* b2         = (const float*)d_in[28];
    float* out = (float*)d_out;

    // ---- workspace (byte offsets) ----
    char* wsb = (char*)d_ws;
    bf16_t* temb_bf = (bf16_t*)(wsb + 0);                 // 19.2 MB
    bf16_t* Gi0     = (bf16_t*)(wsb + 19200000);          // 36.86 MB
    bf16_t* Gi1     = (bf16_t*)(wsb + 56064000);          // 36.86 MB (ends 92,928,000)
    //   VAE aliases (before GRU, inside Gi1):
    float*  mlbuf   = (float*)(wsb + 56064000);           // 8.19 MB
    float*  recb    = (float*)(wsb + 64256000);           // 8.19 MB
    //   GAT aliases (after GRU, inside temb/Gi0):
    bf16_t* xp1b    = (bf16_t*)(wsb + 0);                 // 10.24 MB (bf16)
    bf16_t* x1b     = (bf16_t*)(wsb + 20480000);          // 10.24 MB
    float*  xp2     = (float*)(wsb + 30720000);           // 4.0 MB
    // persistent weights / state
    bf16_t* wih0_bf = (bf16_t*)(wsb + 92928000);
    bf16_t* whh0_bf = (bf16_t*)(wsb + 93419520);
    bf16_t* wih1_bf = (bf16_t*)(wsb + 93812736);
    bf16_t* whh1_bf = (bf16_t*)(wsb + 94205952);
    bf16_t* wml_bf  = (bf16_t*)(wsb + 94599168);
    bf16_t* wdec_bf = (bf16_t*)(wsb + 95123456);
    bf16_t* w1t_bf  = (bf16_t*)(wsb + 95385600);
    bf16_t* w2t_bf  = (bf16_t*)(wsb + 95648000);
    float*  b_ml    = (float*)(wsb + 95750400);
    bf16_t* ufeats_bf = (bf16_t*)(wsb + 95752448);
    bf16_t* out0    = (bf16_t*)(wsb + 99848448);          // 4 slots x 3,072,000
    float*  h0f     = (float*)(wsb + 112136448);
    float*  h1f     = (float*)(wsb + 118280448);
    bf16_t* h0b_init = (bf16_t*)(wsb + 124424448);
    bf16_t* h1init  = (bf16_t*)(wsb + 127496448);
    bf16_t* h1sA    = (bf16_t*)(wsb + 130568448);
    bf16_t* h1sB    = (bf16_t*)(wsb + 133640448);
    bf16_t* xin_bf  = (bf16_t*)(wsb + 136712448);
    int*    deg     = (int*)(wsb + 141832448);
    int*    dcnt    = (int*)(wsb + 141872448);
    int*    rowptr  = (int*)(wsb + 141912448);
    int*    csrc    = (int*)(wsb + 141952512);
    float*  asn1    = (float*)(wsb + 142312512);
    float*  adn1    = (float*)(wsb + 142632512);
    float*  asn2    = (float*)(wsb + 142952512);
    float*  adn2    = (float*)(wsb + 142992512);

    const int TB = 256;
    auto blocks = [](int n) { return (n + 255) / 256; };
    auto ggrid = [](int M, int N) { return dim3((N + 127) / 128, (M + 127) / 128); };

    // ---- prep ----
    PrepArgs pa;
    auto seg = [&](int k, const float* s, bf16_t* dst, int rows, int cin, int cout, int tr) {
        pa.seg[k] = SegD{s, dst, rows, cin, cout, tr};
    };
    seg(0, temb, temb_bf, V_, D_, DP_, 0);
    seg(1, w_ih0, wih0_bf, 3 * H_, D_, DP_, 0);
    seg(2, w_hh0, whh0_bf, 3 * H_, H_, H_, 0);
    seg(3, w_ih1, wih1_bf, 3 * H_, H_, H_, 0);
    seg(4, w_hh1, whh1_bf, 3 * H_, H_, H_, 0);
    seg(5, w_mu, wml_bf, Z_, F_, F_, 0);
    seg(6, w_lv, wml_bf + (size_t)Z_ * F_, Z_, F_, F_, 0);
    seg(7, w_dec, wdec_bf, F_, Z_, Z_, 0);
    seg(8, user_feats, ufeats_bf, NU_, F_, F_, 0);
    seg(9, w1, w1t_bf, HEADS_ * H1_, 0, H_, 1);
    seg(10, w2, w2t_bf, H2_, 0, HEADS_ * H1_, 1);
    pa.nseg = 11;
    long long acc = 0;
    for (int k = 0; k < 11; k++) {
        pa.base[k] = acc;
        acc += (long long)pa.seg[k].rows * pa.seg[k].cout;
    }
    pa.base[11] = acc;
    pa.total = acc;
    hipLaunchKernelGGL(prep_kern, dim3(6144), dim3(TB), 0, stream, pa);

    hipLaunchKernelGGL(init_all, dim3(blocks(NT_ * H_)), dim3(TB), 0, stream,
                       h0in, h0f, h1f, h0b_init, h1init,
                       deg, dcnt, out + N_ * H2_, b_ml, b_mu, b_lv);

    // ---- CSR build ----
    hipLaunchKernelGGL(csr_hist, dim3(blocks(E2_)), dim3(TB), 0, stream, ei, deg);
    hipLaunchKernelGGL(csr_scan, dim3(1), dim3(TB), 0, stream, deg, rowptr);
    hipLaunchKernelGGL(csr_scatter, dim3(blocks(E2_)), dim3(TB), 0, stream,
                       ei, rowptr, dcnt, csrc);

    // ---- VAE ----
    hipLaunchKernelGGL((mfma_gemm<0, false>), ggrid(NU_, 2 * Z_), dim3(TB), 0, stream,
                       ufeats_bf, wml_bf, b_ml, mlbuf, (bf16_t*)nullptr,
                       NU_, 2 * Z_, F_, 2 * Z_, (const int*)nullptr, 0);
    bf16_t* z_bf = xin_bf + (size_t)B_ * H_;
    hipLaunchKernelGGL(vae_z_kl, dim3(256), dim3(TB), 0, stream,
                       mlbuf, veps, z_bf, out + N_ * H2_);
    hipLaunchKernelGGL((mfma_gemm<0, false>), ggrid(NU_, F_), dim3(TB), 0, stream,
                       z_bf, wdec_bf, b_dec, recb, (bf16_t*)nullptr,
                       NU_, F_, Z_, F_, (const int*)nullptr, 0);
    hipLaunchKernelGGL(rec_loss_kern, dim3(256), dim3(TB), 0, stream,
                       recb, user_feats, out + N_ * H2_ + 1);

    // ---- 2-layer GRU: chunked gi GEMMs + paired per-step recurrence ----
    const int MC = TCH_ * NT_;
    auto recL0 = [&](int c, int s) -> RecLay {
        RecLay L;
        L.Gi = Gi0 + (size_t)s * NT_ * 3 * H_;
        L.Wh = whh0_bf; L.bhh = b_hh0;
        L.hprev = (c == 0 && s == 0) ? h0b_init
                : (s == 0) ? out0 + (size_t)3 * NT_ * H_
                           : out0 + (size_t)(s - 1) * NT_ * H_;
        L.hout = out0 + (size_t)s * NT_ * H_;
        L.hf = h0f;
        return L;
    };
    auto recL1 = [&](int c, int s) -> RecLay {
        int t = 4 * c + s;
        RecLay L;
        L.Gi = Gi1 + (size_t)s * NT_ * 3 * H_;
        L.Wh = whh1_bf; L.bhh = b_hh1;
        L.hprev = (t == 0) ? h1init : (((t - 1) & 1) ? h1sB : h1sA);
        L.hout = (t & 1) ? h1sB : h1sA;
        L.hf = h1f;
        return L;
    };

    // chunk 0: L0 only
    hipLaunchKernelGGL((mfma_gemm<1, true>), ggrid(MC, 3 * H_), dim3(TB), 0, stream,
                       temb_bf, wih0_bf, b_ih0, (float*)nullptr, Gi0,
                       MC, 3 * H_, DP_, 3 * H_, gnf, 0);
    for (int s = 0; s < TCH_; s++) {
        RecLay L = recL0(0, s);
        hipLaunchKernelGGL(gru_rec_step, dim3(H_ / 32, YB_), dim3(TB), 0, stream, L, L);
    }
    // chunks 1..5: paired (L0 chunk c, L1 chunk c-1)
    for (int c = 1; c < T_ / TCH_; c++) {
        hipLaunchKernelGGL((mfma_gemm<0, true>), ggrid(MC, 3 * H_), dim3(TB), 0, stream,
                           out0, wih1_bf, b_ih1, (float*)nullptr, Gi1,
                           MC, 3 * H_, H_, 3 * H_, (const int*)nullptr, 0);
        hipLaunchKernelGGL((mfma_gemm<1, true>), ggrid(MC, 3 * H_), dim3(TB), 0, stream,
                           temb_bf, wih0_bf, b_ih0, (float*)nullptr, Gi0,
                           MC, 3 * H_, DP_, 3 * H_, gnf, 4 * c);
        for (int s = 0; s < TCH_; s++) {
            RecLay L0 = recL0(c, s), L1 = recL1(c - 1, s);
            hipLaunchKernelGGL(gru_rec_step, dim3(H_ / 32, 2 * YB_), dim3(TB), 0, stream,
                               L0, L1);
        }
    }
    // final: L1 chunk 5
    hipLaunchKernelGGL((mfma_gemm<0, true>), ggrid(MC, 3 * H_), dim3(TB), 0, stream,
                       out0, wih1_bf, b_ih1, (float*)nullptr, Gi1,
                       MC, 3 * H_, H_, 3 * H_, (const int*)nullptr, 0);
    for (int s = 0; s < TCH_; s++) {
        RecLay L = recL1(T_ / TCH_ - 1, s);
        hipLaunchKernelGGL(gru_rec_step, dim3(H_ / 32, YB_), dim3(TB), 0, stream, L, L);
    }

    // ---- assemble x_in ----
    hipLaunchKernelGGL(assemble_xin, dim3(blocks(NT_ * H_)), dim3(TB), 0, stream,
                       h1f, xin_bf);

    // ---- GAT layer 1 (xp1 in bf16) ----
    hipLaunchKernelGGL((mfma_gemm<0, true>), ggrid(N_, HEADS_ * H1_), dim3(TB), 0, stream,
                       xin_bf, w1t_bf, (const float*)nullptr, (float*)nullptr, xp1b,
                       N_, HEADS_ * H1_, H_, HEADS_ * H1_, (const int*)nullptr, 0);
    hipLaunchKernelGGL(gat_attn_coef_bf, dim3(blocks(N_ * HEADS_)), dim3(TB), 0, stream,
                       xp1b, a_src1, a_dst1, asn1, adn1, HEADS_, H1_);
    hipLaunchKernelGGL(gat_agg1, dim3(N_), dim3(TB), 0, stream,
                       rowptr, csrc, asn1, adn1, xp1b, b1, x1b);

    // ---- GAT layer 2 ----
    hipLaunchKernelGGL((mfma_gemm<0, false>), ggrid(N_, H2_), dim3(TB), 0, stream,
                       x1b, w2t_bf, (const float*)nullptr, xp2, (bf16_t*)nullptr,
                       N_, H2_, HEADS_ * H1_, H2_, (const int*)nullptr, 0);
    hipLaunchKernelGGL(gat_attn_coef, dim3(blocks(N_)), dim3(TB), 0, stream,
                       xp2, a_src2, a_dst2, asn2, adn2, 1, H2_);
    hipLaunchKernelGGL(gat_agg2, dim3((N_ + 3) / 4), dim3(TB), 0, stream,
                       rowptr, csrc, asn2, adn2, xp2, b2, out);

    (void)in_sizes; (void)n_in; (void)out_size; (void)ws_size;
}

// Round 8
// 1970.271 us; speedup vs baseline: 1.1552x; 1.0909x over previous
//
#include <hip/hip_runtime.h>

// ---- problem dims (fixed by reference) ----
#define V_ 30000
#define D_ 300
#define DP_ 320
#define T_ 24
#define H_ 256
#define NT_ 6000
#define NU_ 4000
#define N_ 10000
#define F_ 512
#define Z_ 256
#define E_ 80000
#define B_ 2000
#define H1_ 64
#define H2_ 100
#define HEADS_ 8
#define E2_ (E_ + N_)
#define TCH_ 4
#define YB_ 47          // row-blocks per layer in rec grid (47*128 >= 6000)

typedef __bf16 bf16_t;
typedef bf16_t bf16x8 __attribute__((ext_vector_type(8)));
typedef float  f32x4  __attribute__((ext_vector_type(4)));

// async global->LDS, 16B per lane; lds dest = base + lane*16 (wave-uniform base)
__device__ __forceinline__ void gll16(const bf16_t* g, bf16_t* l)
{
    __builtin_amdgcn_global_load_lds(
        (const __attribute__((address_space(1))) void*)g,
        (__attribute__((address_space(3))) void*)l, 16, 0, 0);
}

// =======================================================================
// 128x128 MFMA GEMM: C = A[M,K] @ B[N,K]^T (+bias).
// - double-buffered global_load_lds staging (1 barrier / K-iter)
// - bf16 output goes through a 32KB XOR-swizzled LDS tile so global
//   stores are full 64B lines (16B/lane coalesced) -- avoids the 1.8x
//   partial-sector write-allocate inflation seen in rocprof (R7).
// - gridDim.z picks cfg g0/g1 (two independent GEMMs of equal M,N in one
//   launch -> no 1128-block tail between the paired chunk GEMMs).
// - gtok != nullptr: A rows gathered (embedding lookup).
// =======================================================================
struct GCfg {
    const bf16_t* A; const bf16_t* B; const float* bias;
    float* Cf; bf16_t* Cb; int M, N, K, ldc;
    const int* gtok; int t0;
};

template<bool OUTBF>
__global__ __launch_bounds__(256) void mfma_gemm(GCfg g0, GCfg g1)
{
    const GCfg g = blockIdx.z ? g1 : g0;
    __shared__ __align__(16) bf16_t SMEM[16384];   // 32 KB
    // A buf b: SMEM + b*4096 ; B buf b: SMEM + 8192 + b*4096 ; C tile: all
    const int tid  = (int)threadIdx.x;
    const int wave = tid >> 6, lane = tid & 63;
    const int quad = lane >> 4, l16 = lane & 15;
    const int mq = (wave & 1) * 64, nq = (wave >> 1) * 64;
    const int mbase = blockIdx.y * 128, nbase = blockIdx.x * 128;
    const int M = g.M, N = g.N, K = g.K, ldc = g.ldc;

    const bf16_t* agp[2];
    const bf16_t* bgp[2];
#pragma unroll
    for (int j = 0; j < 2; j++) {
        int i = wave * 128 + j * 64 + lane;
        int c = i >> 7, row = i & 127;
        int r = mbase + row; if (r >= M) r = M - 1;
        int src = g.gtok ? g.gtok[(r % NT_) * T_ + g.t0 + (r / NT_)] : r;
        agp[j] = g.A + (size_t)src * K + c * 8;
        int rb = nbase + row; if (rb >= N) rb = N - 1;
        bgp[j] = g.B + (size_t)rb * K + c * 8;
    }

    f32x4 acc[4][4];
#pragma unroll
    for (int mi = 0; mi < 4; mi++)
#pragma unroll
        for (int ni = 0; ni < 4; ni++) acc[mi][ni] = (f32x4){0.f, 0.f, 0.f, 0.f};

    auto stage = [&](int b, int k0) {
        bf16_t* ab = SMEM + b * 4096 + wave * 1024;
        bf16_t* bb = SMEM + 8192 + b * 4096 + wave * 1024;
        gll16(agp[0] + k0, ab);
        gll16(agp[1] + k0, ab + 512);
        gll16(bgp[0] + k0, bb);
        gll16(bgp[1] + k0, bb + 512);
    };

    const int niter = K >> 5;
    stage(0, 0);
    for (int ks = 0; ks < niter; ks++) {
        __syncthreads();                       // buf[ks&1] ready, prev reads done
        if (ks + 1 < niter) stage((ks + 1) & 1, (ks + 1) * 32);
        const bf16_t* Ab = SMEM + (ks & 1) * 4096;
        const bf16_t* Bb = SMEM + 8192 + (ks & 1) * 4096;
        bf16x8 afr[4], bfr[4];
#pragma unroll
        for (int mi = 0; mi < 4; mi++)
            afr[mi] = *(const bf16x8*)(Ab + (size_t)(quad * 128 + mq + mi * 16 + l16) * 8);
#pragma unroll
        for (int ni = 0; ni < 4; ni++)
            bfr[ni] = *(const bf16x8*)(Bb + (size_t)(quad * 128 + nq + ni * 16 + l16) * 8);
#pragma unroll
        for (int mi = 0; mi < 4; mi++)
#pragma unroll
            for (int ni = 0; ni < 4; ni++)
                acc[mi][ni] = __builtin_amdgcn_mfma_f32_16x16x32_bf16(
                    afr[mi], bfr[ni], acc[mi][ni], 0, 0, 0);
    }

    if (OUTBF) {
        // stage C into LDS (XOR-swizzled), then full-line coalesced stores
        __syncthreads();
#pragma unroll
        for (int ni = 0; ni < 4; ni++) {
            int colc = nq + ni * 16 + l16;
            float bv = g.bias ? g.bias[nbase + colc] : 0.f;
            int cc = colc >> 3, off = colc & 7;
#pragma unroll
            for (int mi = 0; mi < 4; mi++)
#pragma unroll
                for (int r = 0; r < 4; r++) {
                    int row = mq + mi * 16 + quad * 4 + r;
                    int sw = (row ^ (row >> 3)) & 7;
                    SMEM[row * 128 + ((cc ^ sw) << 3) + off] =
                        (bf16_t)(acc[mi][ni][r] + bv);
                }
        }
        __syncthreads();
        {
            int row = tid >> 1, seg = tid & 1;
            int sw = (row ^ (row >> 3)) & 7;
            int growr = mbase + row;
            if (growr < M) {
#pragma unroll
                for (int q = 0; q < 8; q++) {
                    int cc = seg * 8 + q;
                    bf16x8 v = *(const bf16x8*)(SMEM + row * 128 + ((cc ^ sw) << 3));
                    *(bf16x8*)(g.Cb + (size_t)growr * ldc + nbase + cc * 8) = v;
                }
            }
        }
    } else {
#pragma unroll
        for (int ni = 0; ni < 4; ni++) {
            int col = nbase + nq + ni * 16 + l16;
            if (col >= N) continue;
            float bv = g.bias ? g.bias[col] : 0.f;
#pragma unroll
            for (int mi = 0; mi < 4; mi++)
#pragma unroll
                for (int r = 0; r < 4; r++) {
                    int row = mbase + mq + mi * 16 + quad * 4 + r;
                    if (row >= M) continue;
                    g.Cf[(size_t)row * ldc + col] = acc[mi][ni][r] + bv;
                }
        }
    }
}

// =======================================================================
// Per-step GRU recurrence. One launch carries TWO independent layer-steps
// (L0 step t, L1 step t-4) via blockIdx.y halves. Block = 128 rows x 32 cols.
// Wh B-fragments in VGPRs (96 VGPR, loaded once, L2-hot). h-tile staged by
// double-buffered global_load_lds (16KB). hout written via LDS re-tile so
// each global store instruction covers full 64B lines.
// =======================================================================
struct RecLay {
    const bf16_t* Gi;      // [NT][768] bf16 (b_ih fused)
    const bf16_t* Wh;      // [768][256]
    const float*  bhh;
    const bf16_t* hprev;   // [NT][256] bf16
    bf16_t*       hout;    // [NT][256] bf16
    float*        hf;      // [NT][256] f32 master
};

__global__ __launch_bounds__(256) void gru_rec_step(RecLay A0, RecLay A1)
{
    const bool second = (blockIdx.y >= YB_);
    const RecLay L = second ? A1 : A0;
    const int byr = second ? (int)blockIdx.y - YB_ : (int)blockIdx.y;

    __shared__ __align__(16) bf16_t SMEM[8192];    // 16 KB (2 x 4096 dbuf)
    const int tid  = (int)threadIdx.x;
    const int wave = tid >> 6, lane = tid & 63;
    const int quad = lane >> 4, l16 = lane & 15;
    const int rw = wave & 1, cw = wave >> 1;
    const int bm = byr * 128;
    const int bn = blockIdx.x * 32;
    const int col = bn + cw * 16 + l16;

    // Wh B-fragments: wfr[g][ks] covers k = ks*32 + quad*8 .. +8
    bf16x8 wfr[3][8];
#pragma unroll
    for (int g = 0; g < 3; g++) {
        const bf16_t* wrow = L.Wh + (size_t)(g * H_ + col) * H_ + quad * 8;
#pragma unroll
        for (int ks = 0; ks < 8; ks++)
            wfr[g][ks] = *(const bf16x8*)(wrow + ks * 32);
    }

    const bf16_t* hgp[2];
#pragma unroll
    for (int j = 0; j < 2; j++) {
        int i = wave * 128 + j * 64 + lane;
        int c = i >> 7, row = i & 127;
        int rg = bm + row; if (rg >= NT_) rg = NT_ - 1;
        hgp[j] = L.hprev + (size_t)rg * H_ + c * 8;
    }

    auto stage = [&](int b, int k0) {
        bf16_t* lb = SMEM + b * 4096 + wave * 1024;
        gll16(hgp[0] + k0, lb);
        gll16(hgp[1] + k0, lb + 512);
    };

    const float bhr = L.bhh[col], bhz = L.bhh[H_ + col], bhn = L.bhh[2 * H_ + col];

    f32x4 acc[4][3];
#pragma unroll
    for (int mi = 0; mi < 4; mi++)
#pragma unroll
        for (int g = 0; g < 3; g++) acc[mi][g] = (f32x4){0.f, 0.f, 0.f, 0.f};

    stage(0, 0);
#pragma unroll
    for (int ks = 0; ks < 8; ks++) {
        __syncthreads();
        if (ks < 7) stage((ks + 1) & 1, (ks + 1) * 32);
        const bf16_t* Ab = SMEM + (ks & 1) * 4096;
        bf16x8 afr[4];
#pragma unroll
        for (int mi = 0; mi < 4; mi++)
            afr[mi] = *(const bf16x8*)(Ab + (size_t)(quad * 128 + rw * 64 + mi * 16 + l16) * 8);
#pragma unroll
        for (int mi = 0; mi < 4; mi++)
#pragma unroll
            for (int g = 0; g < 3; g++)
                acc[mi][g] = __builtin_amdgcn_mfma_f32_16x16x32_bf16(
                    afr[mi], wfr[g][ks], acc[mi][g], 0, 0, 0);
    }

    // gate epilogue: hf (f32, full-line stores) direct; hout via LDS re-tile
    float hv[4][4];
#pragma unroll
    for (int mi = 0; mi < 4; mi++)
#pragma unroll
        for (int r = 0; r < 4; r++) {
            int m = bm + rw * 64 + mi * 16 + quad * 4 + r;
            int mc = m < NT_ ? m : NT_ - 1;
            const bf16_t* gim = L.Gi + (size_t)mc * (3 * H_);
            float ir = (float)gim[col];
            float iz = (float)gim[H_ + col];
            float in_ = (float)gim[2 * H_ + col];
            float hr = acc[mi][0][r] + bhr;
            float hz = acc[mi][1][r] + bhz;
            float hn = acc[mi][2][r] + bhn;
            float rg = 1.f / (1.f + expf(-(ir + hr)));
            float zg = 1.f / (1.f + expf(-(iz + hz)));
            float ng = tanhf(in_ + rg * hn);
            size_t o2 = (size_t)mc * H_ + col;
            float hnew = (1.f - zg) * ng + zg * L.hf[o2];
            if (m < NT_) L.hf[o2] = hnew;
            hv[mi][r] = hnew;
        }
    __syncthreads();                       // all staging reads done; reuse SMEM
#pragma unroll
    for (int mi = 0; mi < 4; mi++)
#pragma unroll
        for (int r = 0; r < 4; r++) {
            int row_l = rw * 64 + mi * 16 + quad * 4 + r;
            SMEM[row_l * 40 + cw * 16 + l16] = (bf16_t)hv[mi][r];
        }
    __syncthreads();
    for (int t = tid; t < 512; t += 256) {
        int row_l = t >> 2, q = t & 3;
        int rg = bm + row_l;
        if (rg < NT_) {
            bf16x8 v = *(const bf16x8*)(SMEM + row_l * 40 + q * 8);
            *(bf16x8*)(L.hout + (size_t)rg * H_ + bn + q * 8) = v;
        }
    }
}

// ---------------- prep: all f32->bf16 conversions in one launch ----------------
struct SegD { const float* src; bf16_t* dst; int rows, cin, cout, transp; };
struct PrepArgs { SegD seg[11]; long long base[12]; int nseg; long long total; };

__global__ void prep_kern(PrepArgs pa)
{
    long long stride = (long long)gridDim.x * blockDim.x;
    for (long long i = (long long)blockIdx.x * blockDim.x + threadIdx.x;
         i < pa.total; i += stride) {
        int k = 0;
        while (k + 1 < pa.nseg && i >= pa.base[k + 1]) k++;
        long long local = i - pa.base[k];
        SegD sg = pa.seg[k];
        int r = (int)(local / sg.cout);
        int c = (int)(local - (long long)r * sg.cout);
        float v;
        if (sg.transp) v = sg.src[(size_t)c * sg.rows + r];
        else           v = (c < sg.cin) ? sg.src[(size_t)r * sg.cin + c] : 0.f;
        sg.dst[local] = (bf16_t)v;
    }
}

// ---------------- fused init ----------------
__global__ void init_all(const float* __restrict__ h0in, float* __restrict__ h0f,
                         float* __restrict__ h1f, bf16_t* __restrict__ h0b,
                         bf16_t* __restrict__ h1b,
                         int* __restrict__ deg, int* __restrict__ dcnt,
                         float* __restrict__ loss2, float* __restrict__ b_ml,
                         const float* __restrict__ b_mu, const float* __restrict__ b_lv)
{
    int i = blockIdx.x * blockDim.x + threadIdx.x;
    if (i < NT_ * H_) {
        float a = h0in[i], b = h0in[NT_ * H_ + i];
        h0f[i] = a; h1f[i] = b;
        h0b[i] = (bf16_t)a; h1b[i] = (bf16_t)b;
    }
    if (i < N_) { deg[i] = 0; dcnt[i] = 0; }
    if (i < 2 * Z_) b_ml[i] = (i < Z_) ? b_mu[i] : b_lv[i - Z_];
    if (i < 2) loss2[i] = 0.f;
}

// ---------------- CSR build (by dst, self-loops appended) ----------------
__device__ __forceinline__ void edge_sd(const int* __restrict__ ei, int e, int& s, int& d)
{
    if (e < E_) { s = ei[e]; d = ei[E_ + e]; }
    else        { s = d = e - E_; }
}

__global__ void csr_hist(const int* __restrict__ ei, int* __restrict__ deg)
{
    int e = blockIdx.x * blockDim.x + threadIdx.x;
    if (e >= E2_) return;
    int s, d; edge_sd(ei, e, s, d);
    atomicAdd(deg + d, 1);
}

__global__ void csr_scan(const int* __restrict__ deg, int* __restrict__ rowptr)
{
    __shared__ int buf[256];
    __shared__ int carry;
    int tid = (int)threadIdx.x;
    if (tid == 0) { carry = 0; rowptr[0] = 0; }
    __syncthreads();
    for (int c0 = 0; c0 < N_; c0 += 256) {
        int i = c0 + tid;
        buf[tid] = (i < N_) ? deg[i] : 0;
        __syncthreads();
        for (int off = 1; off < 256; off <<= 1) {
            int t = (tid >= off) ? buf[tid - off] : 0;
            __syncthreads();
            buf[tid] += t;
            __syncthreads();
        }
        if (i < N_) rowptr[i + 1] = carry + buf[tid];
        __syncthreads();
        if (tid == 255) carry += buf[255];
        __syncthreads();
    }
}

__global__ void csr_scatter(const int* __restrict__ ei, const int* __restrict__ rowptr,
                            int* __restrict__ dcnt, int* __restrict__ csrc)
{
    int e = blockIdx.x * blockDim.x + threadIdx.x;
    if (e >= E2_) return;
    int s, d; edge_sd(ei, e, s, d);
    int pos = rowptr[d] + atomicAdd(dcnt + d, 1);
    csrc[pos] = s;
}

// ---------------- VAE (grid-stride; 256 atomics) ----------------
__global__ __launch_bounds__(256) void vae_z_kl(
    const float* __restrict__ ml, const float* __restrict__ eps,
    bf16_t* __restrict__ z_out, float* __restrict__ kl_out)
{
    float t = 0.f;
    int stride = (int)gridDim.x * 256;
    for (int idx = blockIdx.x * 256 + threadIdx.x; idx < NU_ * Z_; idx += stride) {
        int row = idx >> 8, c = idx & 255;
        float m = ml[(size_t)row * 512 + c];
        float l = ml[(size_t)row * 512 + 256 + c];
        float el = expf(l);
        z_out[idx] = (bf16_t)(m + expf(0.5f * l) * eps[idx]);
        t += -0.5f * (1.f + l - m * m - el);
    }
    __shared__ float red[256];
    red[threadIdx.x] = t;
    __syncthreads();
    for (int s = 128; s > 0; s >>= 1) {
        if ((int)threadIdx.x < s) red[threadIdx.x] += red[threadIdx.x + s];
        __syncthreads();
    }
    if (threadIdx.x == 0) atomicAdd(kl_out, red[0] * (1.f / NU_));
}

__global__ __launch_bounds__(256) void rec_loss_kern(
    const float* __restrict__ rec, const float* __restrict__ uf,
    float* __restrict__ loss_out)
{
    float t = 0.f;
    int stride = (int)gridDim.x * 256;
    for (int idx = blockIdx.x * 256 + threadIdx.x; idx < NU_ * F_; idx += stride) {
        float d = rec[idx] - uf[idx];
        t += d * d;
    }
    __shared__ float red[256];
    red[threadIdx.x] = t;
    __syncthreads();
    for (int s = 128; s > 0; s >>= 1) {
        if ((int)threadIdx.x < s) red[threadIdx.x] += red[threadIdx.x + s];
        __syncthreads();
    }
    if (threadIdx.x == 0) atomicAdd(loss_out, red[0] * (1.f / (NU_ * F_)));
}

// ---------------- assemble x_in = [hn[:B], z, hn[B:]] (bf16) ----------------
__global__ void assemble_xin(const float* __restrict__ h1, bf16_t* __restrict__ x_in)
{
    int idx = blockIdx.x * blockDim.x + threadIdx.x;
    if (idx >= NT_ * H_) return;
    int row = idx >> 8, col = idx & 255;
    int dst = (row < B_) ? row : (row + NU_);
    x_in[(size_t)dst * H_ + col] = (bf16_t)h1[idx];
}

// ---------------- GAT ----------------
__global__ void gat_attn_coef_bf(const bf16_t* __restrict__ xp,
                                 const float* __restrict__ a_src,
                                 const float* __restrict__ a_dst,
                                 float* __restrict__ asn, float* __restrict__ adn,
                                 int heads, int C)
{
    int i = blockIdx.x * blockDim.x + threadIdx.x;
    if (i >= N_ * heads) return;
    int node = i / heads, h = i - node * heads;
    const bf16_t* x = xp + (size_t)(node * heads + h) * C;
    float s = 0.f, d = 0.f;
    for (int c8 = 0; c8 < C; c8 += 8) {
        bf16x8 v = *(const bf16x8*)(x + c8);
#pragma unroll
        for (int j = 0; j < 8; j++) {
            float vv = (float)v[j];
            s += vv * a_src[h * C + c8 + j];
            d += vv * a_dst[h * C + c8 + j];
        }
    }
    asn[i] = s;
    adn[i] = d;
}

__global__ void gat_attn_coef(const float* __restrict__ xp, const float* __restrict__ a_src,
                              const float* __restrict__ a_dst, float* __restrict__ asn,
                              float* __restrict__ adn, int heads, int C)
{
    int i = blockIdx.x * blockDim.x + threadIdx.x;
    if (i >= N_ * heads) return;
    int node = i / heads, h = i - node * heads;
    const float* x = xp + (size_t)(node * heads + h) * C;
    float s = 0.f, d = 0.f;
    for (int c = 0; c < C; c++) {
        float v = x[c];
        s += v * a_src[h * C + c];
        d += v * a_dst[h * C + c];
    }
    asn[i] = s;
    adn[i] = d;
}

// fused edge-softmax + aggregate, layer 1: BLOCK per dst, all 8 heads.
__global__ __launch_bounds__(256) void gat_agg1(
    const int* __restrict__ rowptr, const int* __restrict__ csrc,
    const float* __restrict__ asn, const float* __restrict__ adn,
    const bf16_t* __restrict__ xp, const float* __restrict__ bias,
    bf16_t* __restrict__ x1out)
{
    int d = blockIdx.x;
    int tid = (int)threadIdx.x;
    int beg = rowptr[d], end = rowptr[d + 1];
    int h0 = tid >> 6, h1 = h0 + 4;
    float ad0 = adn[d * 8 + h0], ad1 = adn[d * 8 + h1];
    float mx0 = -1e30f, mx1 = -1e30f;
    for (int e = beg; e < end; e++) {
        int s = csrc[e];
        float l0 = asn[s * 8 + h0] + ad0; l0 = (l0 > 0.f) ? l0 : 0.2f * l0;
        float l1 = asn[s * 8 + h1] + ad1; l1 = (l1 > 0.f) ? l1 : 0.2f * l1;
        mx0 = fmaxf(mx0, l0); mx1 = fmaxf(mx1, l1);
    }
    float den0 = 0.f, den1 = 0.f, acc0 = 0.f, acc1 = 0.f;
    for (int e = beg; e < end; e++) {
        int s = csrc[e];
        float l0 = asn[s * 8 + h0] + ad0; l0 = (l0 > 0.f) ? l0 : 0.2f * l0;
        float l1 = asn[s * 8 + h1] + ad1; l1 = (l1 > 0.f) ? l1 : 0.2f * l1;
        float p0 = expf(l0 - mx0), p1 = expf(l1 - mx1);
        den0 += p0; den1 += p1;
        acc0 += p0 * (float)xp[(size_t)s * 512 + tid];
        acc1 += p1 * (float)xp[(size_t)s * 512 + 256 + tid];
    }
    x1out[(size_t)d * 512 + tid]       = (bf16_t)(bias[tid] + acc0 / den0);
    x1out[(size_t)d * 512 + 256 + tid] = (bf16_t)(bias[256 + tid] + acc1 / den1);
}

// fused edge-softmax + aggregate, layer 2 (1 head x 100ch): wave per dst
__global__ __launch_bounds__(256) void gat_agg2(
    const int* __restrict__ rowptr, const int* __restrict__ csrc,
    const float* __restrict__ asn, const float* __restrict__ adn,
    const float* __restrict__ xp, const float* __restrict__ bias,
    float* __restrict__ outp)
{
    int d = blockIdx.x * 4 + ((int)threadIdx.x >> 6);
    if (d >= N_) return;
    int lane = (int)threadIdx.x & 63;
    int beg = rowptr[d], end = rowptr[d + 1];
    float adnd = adn[d];
    float mx = -1e30f;
    for (int e = beg; e < end; e++) {
        float l = asn[csrc[e]] + adnd;
        l = (l > 0.f) ? l : 0.2f * l;
        mx = fmaxf(mx, l);
    }
    float den = 0.f, acc0 = 0.f, acc1 = 0.f;
    for (int e = beg; e < end; e++) {
        int s = csrc[e];
        float l = asn[s] + adnd;
        l = (l > 0.f) ? l : 0.2f * l;
        float p = expf(l - mx);
        den += p;
        acc0 += p * xp[(size_t)s * H2_ + lane];
        if (lane < H2_ - 64) acc1 += p * xp[(size_t)s * H2_ + 64 + lane];
    }
    outp[(size_t)d * H2_ + lane] = bias[lane] + acc0 / den;
    if (lane < H2_ - 64)
        outp[(size_t)d * H2_ + 64 + lane] = bias[64 + lane] + acc1 / den;
}

// ---------------- launcher ----------------
extern "C" void kernel_launch(void* const* d_in, const int* in_sizes, int n_in,
                              void* d_out, int out_size, void* d_ws, size_t ws_size,
                              hipStream_t stream)
{
    const float* user_feats = (const float*)d_in[1];
    const int*   gnf        = (const int*)d_in[2];
    const int*   ei         = (const int*)d_in[3];
    const float* temb       = (const float*)d_in[4];
    const float* w_ih0      = (const float*)d_in[5];
    const float* w_hh0      = (const float*)d_in[6];
    const float* b_ih0      = (const float*)d_in[7];
    const float* b_hh0      = (const float*)d_in[8];
    const float* w_ih1      = (const float*)d_in[9];
    const float* w_hh1      = (const float*)d_in[10];
    const float* b_ih1      = (const float*)d_in[11];
    const float* b_hh1      = (const float*)d_in[12];
    const float* h0in       = (const float*)d_in[13];
    const float* w_mu       = (const float*)d_in[14];
    const float* b_mu       = (const float*)d_in[15];
    const float* w_lv       = (const float*)d_in[16];
    const float* b_lv       = (const float*)d_in[17];
    const float* w_dec      = (const float*)d_in[18];
    const float* b_dec      = (const float*)d_in[19];
    const float* veps       = (const float*)d_in[20];
    const float* w1         = (const float*)d_in[21];
    const float* a_src1     = (const float*)d_in[22];
    const float* a_dst1     = (const float*)d_in[23];
    const float* b1         = (const float*)d_in[24];
    const float* w2         = (const float*)d_in[25];
    const float* a_src2     = (const float*)d_in[26];
    const float* a_dst2     = (const float*)d_in[27];
    const float* b2         = (const float*)d_in[28];
    float* out = (float*)d_out;

    // ---- workspace (byte offsets) ----
    char* wsb = (char*)d_ws;
    bf16_t* temb_bf = (bf16_t*)(wsb + 0);                 // 19.2 MB
    bf16_t* Gi0     = (bf16_t*)(wsb + 19200000);          // 36.86 MB
    bf16_t* Gi1     = (bf16_t*)(wsb + 56064000);          // 36.86 MB (ends 92,928,000)
    float*  mlbuf   = (float*)(wsb + 56064000);           // VAE alias in Gi1
    float*  recb    = (float*)(wsb + 64256000);
    bf16_t* xp1b    = (bf16_t*)(wsb + 0);                 // GAT alias in temb
    bf16_t* x1b     = (bf16_t*)(wsb + 20480000);
    float*  xp2     = (float*)(wsb + 30720000);
    bf16_t* wih0_bf = (bf16_t*)(wsb + 92928000);
    bf16_t* whh0_bf = (bf16_t*)(wsb + 93419520);
    bf16_t* wih1_bf = (bf16_t*)(wsb + 93812736);
    bf16_t* whh1_bf = (bf16_t*)(wsb + 94205952);
    bf16_t* wml_bf  = (bf16_t*)(wsb + 94599168);
    bf16_t* wdec_bf = (bf16_t*)(wsb + 95123456);
    bf16_t* w1t_bf  = (bf16_t*)(wsb + 95385600);
    bf16_t* w2t_bf  = (bf16_t*)(wsb + 95648000);
    float*  b_ml    = (float*)(wsb + 95750400);
    bf16_t* ufeats_bf = (bf16_t*)(wsb + 95752448);
    bf16_t* out0    = (bf16_t*)(wsb + 99848448);          // 4 slots x 3,072,000
    float*  h0f     = (float*)(wsb + 112136448);
    float*  h1f     = (float*)(wsb + 118280448);
    bf16_t* h0b_init = (bf16_t*)(wsb + 124424448);
    bf16_t* h1init  = (bf16_t*)(wsb + 127496448);
    bf16_t* h1sA    = (bf16_t*)(wsb + 130568448);
    bf16_t* h1sB    = (bf16_t*)(wsb + 133640448);
    bf16_t* xin_bf  = (bf16_t*)(wsb + 136712448);
    int*    deg     = (int*)(wsb + 141832448);
    int*    dcnt    = (int*)(wsb + 141872448);
    int*    rowptr  = (int*)(wsb + 141912448);
    int*    csrc    = (int*)(wsb + 141952512);
    float*  asn1    = (float*)(wsb + 142312512);
    float*  adn1    = (float*)(wsb + 142632512);
    float*  asn2    = (float*)(wsb + 142952512);
    float*  adn2    = (float*)(wsb + 142992512);

    const int TB = 256;
    auto blocks = [](int n) { return (n + 255) / 256; };

    auto mkcfg = [](const bf16_t* A, const bf16_t* B, const float* bias,
                    float* Cf, bf16_t* Cb, int M, int N, int K, int ldc,
                    const int* gtok, int t0) {
        GCfg g; g.A = A; g.B = B; g.bias = bias; g.Cf = Cf; g.Cb = Cb;
        g.M = M; g.N = N; g.K = K; g.ldc = ldc; g.gtok = gtok; g.t0 = t0;
        return g;
    };
    auto launch_bf = [&](GCfg g0, GCfg g1, int z) {
        dim3 grid((g0.N + 127) / 128, (g0.M + 127) / 128, z);
        hipLaunchKernelGGL((mfma_gemm<true>), grid, dim3(TB), 0, stream, g0, g1);
    };
    auto launch_f32 = [&](GCfg g0) {
        dim3 grid((g0.N + 127) / 128, (g0.M + 127) / 128, 1);
        hipLaunchKernelGGL((mfma_gemm<false>), grid, dim3(TB), 0, stream, g0, g0);
    };

    // ---- prep ----
    PrepArgs pa;
    auto seg = [&](int k, const float* s, bf16_t* dst, int rows, int cin, int cout, int tr) {
        pa.seg[k] = SegD{s, dst, rows, cin, cout, tr};
    };
    seg(0, temb, temb_bf, V_, D_, DP_, 0);
    seg(1, w_ih0, wih0_bf, 3 * H_, D_, DP_, 0);
    seg(2, w_hh0, whh0_bf, 3 * H_, H_, H_, 0);
    seg(3, w_ih1, wih1_bf, 3 * H_, H_, H_, 0);
    seg(4, w_hh1, whh1_bf, 3 * H_, H_, H_, 0);
    seg(5, w_mu, wml_bf, Z_, F_, F_, 0);
    seg(6, w_lv, wml_bf + (size_t)Z_ * F_, Z_, F_, F_, 0);
    seg(7, w_dec, wdec_bf, F_, Z_, Z_, 0);
    seg(8, user_feats, ufeats_bf, NU_, F_, F_, 0);
    seg(9, w1, w1t_bf, HEADS_ * H1_, 0, H_, 1);
    seg(10, w2, w2t_bf, H2_, 0, HEADS_ * H1_, 1);
    pa.nseg = 11;
    long long acc = 0;
    for (int k = 0; k < 11; k++) {
        pa.base[k] = acc;
        acc += (long long)pa.seg[k].rows * pa.seg[k].cout;
    }
    pa.base[11] = acc;
    pa.total = acc;
    hipLaunchKernelGGL(prep_kern, dim3(6144), dim3(TB), 0, stream, pa);

    hipLaunchKernelGGL(init_all, dim3(blocks(NT_ * H_)), dim3(TB), 0, stream,
                       h0in, h0f, h1f, h0b_init, h1init,
                       deg, dcnt, out + N_ * H2_, b_ml, b_mu, b_lv);

    // ---- CSR build ----
    hipLaunchKernelGGL(csr_hist, dim3(blocks(E2_)), dim3(TB), 0, stream, ei, deg);
    hipLaunchKernelGGL(csr_scan, dim3(1), dim3(TB), 0, stream, deg, rowptr);
    hipLaunchKernelGGL(csr_scatter, dim3(blocks(E2_)), dim3(TB), 0, stream,
                       ei, rowptr, dcnt, csrc);

    // ---- VAE ----
    launch_f32(mkcfg(ufeats_bf, wml_bf, b_ml, mlbuf, nullptr,
                     NU_, 2 * Z_, F_, 2 * Z_, nullptr, 0));
    bf16_t* z_bf = xin_bf + (size_t)B_ * H_;
    hipLaunchKernelGGL(vae_z_kl, dim3(256), dim3(TB), 0, stream,
                       mlbuf, veps, z_bf, out + N_ * H2_);
    launch_f32(mkcfg(z_bf, wdec_bf, b_dec, recb, nullptr,
                     NU_, F_, Z_, F_, nullptr, 0));
    hipLaunchKernelGGL(rec_loss_kern, dim3(256), dim3(TB), 0, stream,
                       recb, user_feats, out + N_ * H2_ + 1);

    // ---- 2-layer GRU: paired chunk gi GEMMs + paired per-step recurrence ----
    const int MC = TCH_ * NT_;
    auto giL0 = [&](int c) {
        return mkcfg(temb_bf, wih0_bf, b_ih0, nullptr, Gi0,
                     MC, 3 * H_, DP_, 3 * H_, gnf, 4 * c);
    };
    auto giL1 = [&]() {
        return mkcfg(out0, wih1_bf, b_ih1, nullptr, Gi1,
                     MC, 3 * H_, H_, 3 * H_, nullptr, 0);
    };
    auto recL0 = [&](int c, int s) -> RecLay {
        RecLay L;
        L.Gi = Gi0 + (size_t)s * NT_ * 3 * H_;
        L.Wh = whh0_bf; L.bhh = b_hh0;
        L.hprev = (c == 0 && s == 0) ? h0b_init
                : (s == 0) ? out0 + (size_t)3 * NT_ * H_
                           : out0 + (size_t)(s - 1) * NT_ * H_;
        L.hout = out0 + (size_t)s * NT_ * H_;
        L.hf = h0f;
        return L;
    };
    auto recL1 = [&](int c, int s) -> RecLay {
        int t = 4 * c + s;
        RecLay L;
        L.Gi = Gi1 + (size_t)s * NT_ * 3 * H_;
        L.Wh = whh1_bf; L.bhh = b_hh1;
        L.hprev = (t == 0) ? h1init : (((t - 1) & 1) ? h1sB : h1sA);
        L.hout = (t & 1) ? h1sB : h1sA;
        L.hf = h1f;
        return L;
    };

    // chunk 0: L0 only
    {
        GCfg g = giL0(0);
        launch_bf(g, g, 1);
    }
    for (int s = 0; s < TCH_; s++) {
        RecLay L = recL0(0, s);
        hipLaunchKernelGGL(gru_rec_step, dim3(H_ / 32, YB_), dim3(TB), 0, stream, L, L);
    }
    // chunks 1..5: paired GEMM (L1 gi of c-1 reads out0 BEFORE L0 recs overwrite;
    // both in one z=2 launch) then paired rec steps
    for (int c = 1; c < T_ / TCH_; c++) {
        launch_bf(giL1(), giL0(c), 2);
        for (int s = 0; s < TCH_; s++) {
            RecLay L0 = recL0(c, s), L1 = recL1(c - 1, s);
            hipLaunchKernelGGL(gru_rec_step, dim3(H_ / 32, 2 * YB_), dim3(TB), 0, stream,
                               L0, L1);
        }
    }
    // final: L1 chunk 5
    {
        GCfg g = giL1();
        launch_bf(g, g, 1);
    }
    for (int s = 0; s < TCH_; s++) {
        RecLay L = recL1(T_ / TCH_ - 1, s);
        hipLaunchKernelGGL(gru_rec_step, dim3(H_ / 32, YB_), dim3(TB), 0, stream, L, L);
    }

    // ---- assemble x_in ----
    hipLaunchKernelGGL(assemble_xin, dim3(blocks(NT_ * H_)), dim3(TB), 0, stream,
                       h1f, xin_bf);

    // ---- GAT layer 1 (xp1 in bf16) ----
    launch_bf(mkcfg(xin_bf, w1t_bf, nullptr, nullptr, xp1b,
                    N_, HEADS_ * H1_, H_, HEADS_ * H1_, nullptr, 0),
              mkcfg(xin_bf, w1t_bf, nullptr, nullptr, xp1b,
                    N_, HEADS_ * H1_, H_, HEADS_ * H1_, nullptr, 0), 1);
    hipLaunchKernelGGL(gat_attn_coef_bf, dim3(blocks(N_ * HEADS_)), dim3(TB), 0, stream,
                       xp1b, a_src1, a_dst1, asn1, adn1, HEADS_, H1_);
    hipLaunchKernelGGL(gat_agg1, dim3(N_), dim3(TB), 0, stream,
                       rowptr, csrc, asn1, adn1, xp1b, b1, x1b);

    // ---- GAT layer 2 ----
    launch_f32(mkcfg(x1b, w2t_bf, nullptr, xp2, nullptr,
                     N_, H2_, HEADS_ * H1_, H2_, nullptr, 0));
    hipLaunchKernelGGL(gat_attn_coef, dim3(blocks(N_)), dim3(TB), 0, stream,
                       xp2, a_src2, a_dst2, asn2, adn2, 1, H2_);
    hipLaunchKernelGGL(gat_agg2, dim3((N_ + 3) / 4), dim3(TB), 0, stream,
                       rowptr, csrc, asn2, adn2, xp2, b2, out);

    (void)in_sizes; (void)n_in; (void)out_size; (void)ws_size;
}

// Round 9
// 1729.141 us; speedup vs baseline: 1.3163x; 1.1395x over previous
//
#include <hip/hip_runtime.h>

// ---- problem dims (fixed by reference) ----
#define V_ 30000
#define D_ 300
#define DP_ 320
#define T_ 24
#define H_ 256
#define NT_ 6000
#define NU_ 4000
#define N_ 10000
#define F_ 512
#define Z_ 256
#define E_ 80000
#define B_ 2000
#define H1_ 64
#define H2_ 100
#define HEADS_ 8
#define E2_ (E_ + N_)
#define TCH_ 4
#define YB_ 47          // row-blocks per layer in rec grid (47*128 >= 6000)

typedef __bf16 bf16_t;
typedef bf16_t bf16x8 __attribute__((ext_vector_type(8)));
typedef float  f32x4  __attribute__((ext_vector_type(4)));

// async global->LDS, 16B per lane; lds dest = base + lane*16 (wave-uniform base)
__device__ __forceinline__ void gll16(const bf16_t* g, bf16_t* l)
{
    __builtin_amdgcn_global_load_lds(
        (const __attribute__((address_space(1))) void*)g,
        (__attribute__((address_space(3))) void*)l, 16, 0, 0);
}

// =======================================================================
// 128x128 MFMA GEMM: C = A[M,K] @ B[N,K]^T (+bias).
// - double-buffered global_load_lds staging (1 barrier / K-iter)
// - bf16 C staged through XOR-swizzled LDS -> full-64B-line stores
// - XCD-aware block swizzle: flat L -> (L&7)*(total/8) + (L>>3) groups a
//   contiguous band of row-panels per XCD (round-robin dispatch) so A rows
//   are fetched ~once per XCD instead of once per column-block (R8: 84.5MB
//   FETCH vs ~28MB ideal was exactly this ~6x A re-fetch).
// - gridDim.z picks cfg g0/g1 (two independent GEMMs in one launch).
// =======================================================================
struct GCfg {
    const bf16_t* A; const bf16_t* B; const float* bias;
    float* Cf; bf16_t* Cb; int M, N, K, ldc;
    const int* gtok; int t0;
};

template<bool OUTBF>
__global__ __launch_bounds__(256) void mfma_gemm(GCfg g0, GCfg g1)
{
    const GCfg g = blockIdx.z ? g1 : g0;
    __shared__ __align__(16) bf16_t SMEM[16384];   // 32 KB
    const int tid  = (int)threadIdx.x;
    const int wave = tid >> 6, lane = tid & 63;
    const int quad = lane >> 4, l16 = lane & 15;
    const int mq = (wave & 1) * 64, nq = (wave >> 1) * 64;

    int bx = (int)blockIdx.x, by = (int)blockIdx.y;
    {
        int gx = (int)gridDim.x, total = gx * (int)gridDim.y;
        if ((total & 7) == 0) {
            int L = by * gx + bx;
            int F = (L & 7) * (total >> 3) + (L >> 3);
            bx = F % gx;
            by = F / gx;
        }
    }
    const int mbase = by * 128, nbase = bx * 128;
    const int M = g.M, N = g.N, K = g.K, ldc = g.ldc;

    const bf16_t* agp[2];
    const bf16_t* bgp[2];
#pragma unroll
    for (int j = 0; j < 2; j++) {
        int i = wave * 128 + j * 64 + lane;
        int c = i >> 7, row = i & 127;
        int r = mbase + row; if (r >= M) r = M - 1;
        int src = g.gtok ? g.gtok[(r % NT_) * T_ + g.t0 + (r / NT_)] : r;
        agp[j] = g.A + (size_t)src * K + c * 8;
        int rb = nbase + row; if (rb >= N) rb = N - 1;
        bgp[j] = g.B + (size_t)rb * K + c * 8;
    }

    f32x4 acc[4][4];
#pragma unroll
    for (int mi = 0; mi < 4; mi++)
#pragma unroll
        for (int ni = 0; ni < 4; ni++) acc[mi][ni] = (f32x4){0.f, 0.f, 0.f, 0.f};

    auto stage = [&](int b, int k0) {
        bf16_t* ab = SMEM + b * 4096 + wave * 1024;
        bf16_t* bb = SMEM + 8192 + b * 4096 + wave * 1024;
        gll16(agp[0] + k0, ab);
        gll16(agp[1] + k0, ab + 512);
        gll16(bgp[0] + k0, bb);
        gll16(bgp[1] + k0, bb + 512);
    };

    const int niter = K >> 5;
    stage(0, 0);
    for (int ks = 0; ks < niter; ks++) {
        __syncthreads();
        if (ks + 1 < niter) stage((ks + 1) & 1, (ks + 1) * 32);
        const bf16_t* Ab = SMEM + (ks & 1) * 4096;
        const bf16_t* Bb = SMEM + 8192 + (ks & 1) * 4096;
        bf16x8 afr[4], bfr[4];
#pragma unroll
        for (int mi = 0; mi < 4; mi++)
            afr[mi] = *(const bf16x8*)(Ab + (size_t)(quad * 128 + mq + mi * 16 + l16) * 8);
#pragma unroll
        for (int ni = 0; ni < 4; ni++)
            bfr[ni] = *(const bf16x8*)(Bb + (size_t)(quad * 128 + nq + ni * 16 + l16) * 8);
#pragma unroll
        for (int mi = 0; mi < 4; mi++)
#pragma unroll
            for (int ni = 0; ni < 4; ni++)
                acc[mi][ni] = __builtin_amdgcn_mfma_f32_16x16x32_bf16(
                    afr[mi], bfr[ni], acc[mi][ni], 0, 0, 0);
    }

    if (OUTBF) {
        __syncthreads();
#pragma unroll
        for (int ni = 0; ni < 4; ni++) {
            int colc = nq + ni * 16 + l16;
            float bv = g.bias ? g.bias[nbase + colc] : 0.f;
            int cc = colc >> 3, off = colc & 7;
#pragma unroll
            for (int mi = 0; mi < 4; mi++)
#pragma unroll
                for (int r = 0; r < 4; r++) {
                    int row = mq + mi * 16 + quad * 4 + r;
                    int sw = (row ^ (row >> 3)) & 7;
                    SMEM[row * 128 + ((cc ^ sw) << 3) + off] =
                        (bf16_t)(acc[mi][ni][r] + bv);
                }
        }
        __syncthreads();
        {
            int row = tid >> 1, seg = tid & 1;
            int sw = (row ^ (row >> 3)) & 7;
            int growr = mbase + row;
            if (growr < M) {
#pragma unroll
                for (int q = 0; q < 8; q++) {
                    int cc = seg * 8 + q;
                    bf16x8 v = *(const bf16x8*)(SMEM + row * 128 + ((cc ^ sw) << 3));
                    *(bf16x8*)(g.Cb + (size_t)growr * ldc + nbase + cc * 8) = v;
                }
            }
        }
    } else {
#pragma unroll
        for (int ni = 0; ni < 4; ni++) {
            int col = nbase + nq + ni * 16 + l16;
            if (col >= N) continue;
            float bv = g.bias ? g.bias[col] : 0.f;
#pragma unroll
            for (int mi = 0; mi < 4; mi++)
#pragma unroll
                for (int r = 0; r < 4; r++) {
                    int row = mbase + mq + mi * 16 + quad * 4 + r;
                    if (row >= M) continue;
                    g.Cf[(size_t)row * ldc + col] = acc[mi][ni][r] + bv;
                }
        }
    }
}

// =======================================================================
// Per-step GRU recurrence, bf16 state only (no f32 master: R4 proved the
// accuracy budget allows it; saves 12.2 MB/step/layer of HBM traffic).
// One launch carries TWO independent layer-steps via blockIdx.y halves.
// Wh B-fragments in VGPRs; h-tile double-buffered via global_load_lds;
// hout re-tiled through LDS for full-line stores.
// =======================================================================
struct RecLay {
    const bf16_t* Gi;      // [NT][768] bf16 (b_ih fused)
    const bf16_t* Wh;      // [768][256]
    const float*  bhh;
    const bf16_t* hprev;   // [NT][256] bf16
    bf16_t*       hout;    // [NT][256] bf16
};

__global__ __launch_bounds__(256) void gru_rec_step(RecLay A0, RecLay A1)
{
    const bool second = (blockIdx.y >= YB_);
    const RecLay L = second ? A1 : A0;
    const int byr = second ? (int)blockIdx.y - YB_ : (int)blockIdx.y;

    __shared__ __align__(16) bf16_t SMEM[8192];    // 16 KB (2 x 4096 dbuf)
    const int tid  = (int)threadIdx.x;
    const int wave = tid >> 6, lane = tid & 63;
    const int quad = lane >> 4, l16 = lane & 15;
    const int rw = wave & 1, cw = wave >> 1;
    const int bm = byr * 128;
    const int bn = blockIdx.x * 32;
    const int col = bn + cw * 16 + l16;

    bf16x8 wfr[3][8];
#pragma unroll
    for (int g = 0; g < 3; g++) {
        const bf16_t* wrow = L.Wh + (size_t)(g * H_ + col) * H_ + quad * 8;
#pragma unroll
        for (int ks = 0; ks < 8; ks++)
            wfr[g][ks] = *(const bf16x8*)(wrow + ks * 32);
    }

    const bf16_t* hgp[2];
#pragma unroll
    for (int j = 0; j < 2; j++) {
        int i = wave * 128 + j * 64 + lane;
        int c = i >> 7, row = i & 127;
        int rg = bm + row; if (rg >= NT_) rg = NT_ - 1;
        hgp[j] = L.hprev + (size_t)rg * H_ + c * 8;
    }

    auto stage = [&](int b, int k0) {
        bf16_t* lb = SMEM + b * 4096 + wave * 1024;
        gll16(hgp[0] + k0, lb);
        gll16(hgp[1] + k0, lb + 512);
    };

    const float bhr = L.bhh[col], bhz = L.bhh[H_ + col], bhn = L.bhh[2 * H_ + col];

    f32x4 acc[4][3];
#pragma unroll
    for (int mi = 0; mi < 4; mi++)
#pragma unroll
        for (int g = 0; g < 3; g++) acc[mi][g] = (f32x4){0.f, 0.f, 0.f, 0.f};

    stage(0, 0);
#pragma unroll
    for (int ks = 0; ks < 8; ks++) {
        __syncthreads();
        if (ks < 7) stage((ks + 1) & 1, (ks + 1) * 32);
        const bf16_t* Ab = SMEM + (ks & 1) * 4096;
        bf16x8 afr[4];
#pragma unroll
        for (int mi = 0; mi < 4; mi++)
            afr[mi] = *(const bf16x8*)(Ab + (size_t)(quad * 128 + rw * 64 + mi * 16 + l16) * 8);
#pragma unroll
        for (int mi = 0; mi < 4; mi++)
#pragma unroll
            for (int g = 0; g < 3; g++)
                acc[mi][g] = __builtin_amdgcn_mfma_f32_16x16x32_bf16(
                    afr[mi], wfr[g][ks], acc[mi][g], 0, 0, 0);
    }

    float hv[4][4];
#pragma unroll
    for (int mi = 0; mi < 4; mi++)
#pragma unroll
        for (int r = 0; r < 4; r++) {
            int m = bm + rw * 64 + mi * 16 + quad * 4 + r;
            int mc = m < NT_ ? m : NT_ - 1;
            const bf16_t* gim = L.Gi + (size_t)mc * (3 * H_);
            float ir = (float)gim[col];
            float iz = (float)gim[H_ + col];
            float in_ = (float)gim[2 * H_ + col];
            float hr = acc[mi][0][r] + bhr;
            float hz = acc[mi][1][r] + bhz;
            float hn = acc[mi][2][r] + bhn;
            float rg = 1.f / (1.f + expf(-(ir + hr)));
            float zg = 1.f / (1.f + expf(-(iz + hz)));
            float ng = tanhf(in_ + rg * hn);
            float hold = (float)L.hprev[(size_t)mc * H_ + col];
            hv[mi][r] = (1.f - zg) * ng + zg * hold;
        }
    __syncthreads();
#pragma unroll
    for (int mi = 0; mi < 4; mi++)
#pragma unroll
        for (int r = 0; r < 4; r++) {
            int row_l = rw * 64 + mi * 16 + quad * 4 + r;
            SMEM[row_l * 40 + cw * 16 + l16] = (bf16_t)hv[mi][r];
        }
    __syncthreads();
    for (int t = tid; t < 512; t += 256) {
        int row_l = t >> 2, q = t & 3;
        int rg = bm + row_l;
        if (rg < NT_) {
            bf16x8 v = *(const bf16x8*)(SMEM + row_l * 40 + q * 8);
            *(bf16x8*)(L.hout + (size_t)rg * H_ + bn + q * 8) = v;
        }
    }
}

// ---------------- prep: all f32->bf16 conversions in one launch ----------------
struct SegD { const float* src; bf16_t* dst; int rows, cin, cout, transp; };
struct PrepArgs { SegD seg[11]; long long base[12]; int nseg; long long total; };

__global__ void prep_kern(PrepArgs pa)
{
    long long stride = (long long)gridDim.x * blockDim.x;
    for (long long i = (long long)blockIdx.x * blockDim.x + threadIdx.x;
         i < pa.total; i += stride) {
        int k = 0;
        while (k + 1 < pa.nseg && i >= pa.base[k + 1]) k++;
        long long local = i - pa.base[k];
        SegD sg = pa.seg[k];
        int r = (int)(local / sg.cout);
        int c = (int)(local - (long long)r * sg.cout);
        float v;
        if (sg.transp) v = sg.src[(size_t)c * sg.rows + r];
        else           v = (c < sg.cin) ? sg.src[(size_t)r * sg.cin + c] : 0.f;
        sg.dst[local] = (bf16_t)v;
    }
}

// ---------------- fused init ----------------
__global__ void init_all(const float* __restrict__ h0in, bf16_t* __restrict__ h0b,
                         bf16_t* __restrict__ h1b,
                         int* __restrict__ deg, int* __restrict__ dcnt,
                         float* __restrict__ loss2, float* __restrict__ b_ml,
                         const float* __restrict__ b_mu, const float* __restrict__ b_lv)
{
    int i = blockIdx.x * blockDim.x + threadIdx.x;
    if (i < NT_ * H_) {
        h0b[i] = (bf16_t)h0in[i];
        h1b[i] = (bf16_t)h0in[NT_ * H_ + i];
    }
    if (i < N_) { deg[i] = 0; dcnt[i] = 0; }
    if (i < 2 * Z_) b_ml[i] = (i < Z_) ? b_mu[i] : b_lv[i - Z_];
    if (i < 2) loss2[i] = 0.f;
}

// ---------------- CSR build (by dst, self-loops appended) ----------------
__device__ __forceinline__ void edge_sd(const int* __restrict__ ei, int e, int& s, int& d)
{
    if (e < E_) { s = ei[e]; d = ei[E_ + e]; }
    else        { s = d = e - E_; }
}

__global__ void csr_hist(const int* __restrict__ ei, int* __restrict__ deg)
{
    int e = blockIdx.x * blockDim.x + threadIdx.x;
    if (e >= E2_) return;
    int s, d; edge_sd(ei, e, s, d);
    atomicAdd(deg + d, 1);
}

__global__ void csr_scan(const int* __restrict__ deg, int* __restrict__ rowptr)
{
    __shared__ int buf[256];
    __shared__ int carry;
    int tid = (int)threadIdx.x;
    if (tid == 0) { carry = 0; rowptr[0] = 0; }
    __syncthreads();
    for (int c0 = 0; c0 < N_; c0 += 256) {
        int i = c0 + tid;
        buf[tid] = (i < N_) ? deg[i] : 0;
        __syncthreads();
        for (int off = 1; off < 256; off <<= 1) {
            int t = (tid >= off) ? buf[tid - off] : 0;
            __syncthreads();
            buf[tid] += t;
            __syncthreads();
        }
        if (i < N_) rowptr[i + 1] = carry + buf[tid];
        __syncthreads();
        if (tid == 255) carry += buf[255];
        __syncthreads();
    }
}

__global__ void csr_scatter(const int* __restrict__ ei, const int* __restrict__ rowptr,
                            int* __restrict__ dcnt, int* __restrict__ csrc)
{
    int e = blockIdx.x * blockDim.x + threadIdx.x;
    if (e >= E2_) return;
    int s, d; edge_sd(ei, e, s, d);
    int pos = rowptr[d] + atomicAdd(dcnt + d, 1);
    csrc[pos] = s;
}

// ---------------- VAE (grid-stride; 256 atomics) ----------------
__global__ __launch_bounds__(256) void vae_z_kl(
    const float* __restrict__ ml, const float* __restrict__ eps,
    bf16_t* __restrict__ z_out, float* __restrict__ kl_out)
{
    float t = 0.f;
    int stride = (int)gridDim.x * 256;
    for (int idx = blockIdx.x * 256 + threadIdx.x; idx < NU_ * Z_; idx += stride) {
        int row = idx >> 8, c = idx & 255;
        float m = ml[(size_t)row * 512 + c];
        float l = ml[(size_t)row * 512 + 256 + c];
        float el = expf(l);
        z_out[idx] = (bf16_t)(m + expf(0.5f * l) * eps[idx]);
        t += -0.5f * (1.f + l - m * m - el);
    }
    __shared__ float red[256];
    red[threadIdx.x] = t;
    __syncthreads();
    for (int s = 128; s > 0; s >>= 1) {
        if ((int)threadIdx.x < s) red[threadIdx.x] += red[threadIdx.x + s];
        __syncthreads();
    }
    if (threadIdx.x == 0) atomicAdd(kl_out, red[0] * (1.f / NU_));
}

__global__ __launch_bounds__(256) void rec_loss_kern(
    const float* __restrict__ rec, const float* __restrict__ uf,
    float* __restrict__ loss_out)
{
    float t = 0.f;
    int stride = (int)gridDim.x * 256;
    for (int idx = blockIdx.x * 256 + threadIdx.x; idx < NU_ * F_; idx += stride) {
        float d = rec[idx] - uf[idx];
        t += d * d;
    }
    __shared__ float red[256];
    red[threadIdx.x] = t;
    __syncthreads();
    for (int s = 128; s > 0; s >>= 1) {
        if ((int)threadIdx.x < s) red[threadIdx.x] += red[threadIdx.x + s];
        __syncthreads();
    }
    if (threadIdx.x == 0) atomicAdd(loss_out, red[0] * (1.f / (NU_ * F_)));
}

// ---------------- assemble x_in = [hn[:B], z, hn[B:]] (bf16 -> bf16) ----------------
__global__ void assemble_xin(const bf16_t* __restrict__ h1, bf16_t* __restrict__ x_in)
{
    int idx = blockIdx.x * blockDim.x + threadIdx.x;
    if (idx >= NT_ * H_) return;
    int row = idx >> 8, col = idx & 255;
    int dst = (row < B_) ? row : (row + NU_);
    x_in[(size_t)dst * H_ + col] = h1[idx];
}

// ---------------- GAT ----------------
__global__ void gat_attn_coef_bf(const bf16_t* __restrict__ xp,
                                 const float* __restrict__ a_src,
                                 const float* __restrict__ a_dst,
                                 float* __restrict__ asn, float* __restrict__ adn,
                                 int heads, int C)
{
    int i = blockIdx.x * blockDim.x + threadIdx.x;
    if (i >= N_ * heads) return;
    int node = i / heads, h = i - node * heads;
    const bf16_t* x = xp + (size_t)(node * heads + h) * C;
    float s = 0.f, d = 0.f;
    for (int c8 = 0; c8 < C; c8 += 8) {
        bf16x8 v = *(const bf16x8*)(x + c8);
#pragma unroll
        for (int j = 0; j < 8; j++) {
            float vv = (float)v[j];
            s += vv * a_src[h * C + c8 + j];
            d += vv * a_dst[h * C + c8 + j];
        }
    }
    asn[i] = s;
    adn[i] = d;
}

__global__ void gat_attn_coef(const float* __restrict__ xp, const float* __restrict__ a_src,
                              const float* __restrict__ a_dst, float* __restrict__ asn,
                              float* __restrict__ adn, int heads, int C)
{
    int i = blockIdx.x * blockDim.x + threadIdx.x;
    if (i >= N_ * heads) return;
    int node = i / heads, h = i - node * heads;
    const float* x = xp + (size_t)(node * heads + h) * C;
    float s = 0.f, d = 0.f;
    for (int c = 0; c < C; c++) {
        float v = x[c];
        s += v * a_src[h * C + c];
        d += v * a_dst[h * C + c];
    }
    asn[i] = s;
    adn[i] = d;
}

// fused edge-softmax + aggregate, layer 1: BLOCK per dst, all 8 heads.
__global__ __launch_bounds__(256) void gat_agg1(
    const int* __restrict__ rowptr, const int* __restrict__ csrc,
    const float* __restrict__ asn, const float* __restrict__ adn,
    const bf16_t* __restrict__ xp, const float* __restrict__ bias,
    bf16_t* __restrict__ x1out)
{
    int d = blockIdx.x;
    int tid = (int)threadIdx.x;
    int beg = rowptr[d], end = rowptr[d + 1];
    int h0 = tid >> 6, h1 = h0 + 4;
    float ad0 = adn[d * 8 + h0], ad1 = adn[d * 8 + h1];
    float mx0 = -1e30f, mx1 = -1e30f;
    for (int e = beg; e < end; e++) {
        int s = csrc[e];
        float l0 = asn[s * 8 + h0] + ad0; l0 = (l0 > 0.f) ? l0 : 0.2f * l0;
        float l1 = asn[s * 8 + h1] + ad1; l1 = (l1 > 0.f) ? l1 : 0.2f * l1;
        mx0 = fmaxf(mx0, l0); mx1 = fmaxf(mx1, l1);
    }
    float den0 = 0.f, den1 = 0.f, acc0 = 0.f, acc1 = 0.f;
    for (int e = beg; e < end; e++) {
        int s = csrc[e];
        float l0 = asn[s * 8 + h0] + ad0; l0 = (l0 > 0.f) ? l0 : 0.2f * l0;
        float l1 = asn[s * 8 + h1] + ad1; l1 = (l1 > 0.f) ? l1 : 0.2f * l1;
        float p0 = expf(l0 - mx0), p1 = expf(l1 - mx1);
        den0 += p0; den1 += p1;
        acc0 += p0 * (float)xp[(size_t)s * 512 + tid];
        acc1 += p1 * (float)xp[(size_t)s * 512 + 256 + tid];
    }
    x1out[(size_t)d * 512 + tid]       = (bf16_t)(bias[tid] + acc0 / den0);
    x1out[(size_t)d * 512 + 256 + tid] = (bf16_t)(bias[256 + tid] + acc1 / den1);
}

// fused edge-softmax + aggregate, layer 2 (1 head x 100ch): wave per dst
__global__ __launch_bounds__(256) void gat_agg2(
    const int* __restrict__ rowptr, const int* __restrict__ csrc,
    const float* __restrict__ asn, const float* __restrict__ adn,
    const float* __restrict__ xp, const float* __restrict__ bias,
    float* __restrict__ outp)
{
    int d = blockIdx.x * 4 + ((int)threadIdx.x >> 6);
    if (d >= N_) return;
    int lane = (int)threadIdx.x & 63;
    int beg = rowptr[d], end = rowptr[d + 1];
    float adnd = adn[d];
    float mx = -1e30f;
    for (int e = beg; e < end; e++) {
        float l = asn[csrc[e]] + adnd;
        l = (l > 0.f) ? l : 0.2f * l;
        mx = fmaxf(mx, l);
    }
    float den = 0.f, acc0 = 0.f, acc1 = 0.f;
    for (int e = beg; e < end; e++) {
        int s = csrc[e];
        float l = asn[s] + adnd;
        l = (l > 0.f) ? l : 0.2f * l;
        float p = expf(l - mx);
        den += p;
        acc0 += p * xp[(size_t)s * H2_ + lane];
        if (lane < H2_ - 64) acc1 += p * xp[(size_t)s * H2_ + 64 + lane];
    }
    outp[(size_t)d * H2_ + lane] = bias[lane] + acc0 / den;
    if (lane < H2_ - 64)
        outp[(size_t)d * H2_ + 64 + lane] = bias[64 + lane] + acc1 / den;
}

// ---------------- launcher ----------------
extern "C" void kernel_launch(void* const* d_in, const int* in_sizes, int n_in,
                              void* d_out, int out_size, void* d_ws, size_t ws_size,
                              hipStream_t stream)
{
    const float* user_feats = (const float*)d_in[1];
    const int*   gnf        = (const int*)d_in[2];
    const int*   ei         = (const int*)d_in[3];
    const float* temb       = (const float*)d_in[4];
    const float* w_ih0      = (const float*)d_in[5];
    const float* w_hh0      = (const float*)d_in[6];
    const float* b_ih0      = (const float*)d_in[7];
    const float* b_hh0      = (const float*)d_in[8];
    const float* w_ih1      = (const float*)d_in[9];
    const float* w_hh1      = (const float*)d_in[10];
    const float* b_ih1      = (const float*)d_in[11];
    const float* b_hh1      = (const float*)d_in[12];
    const float* h0in       = (const float*)d_in[13];
    const float* w_mu       = (const float*)d_in[14];
    const float* b_mu       = (const float*)d_in[15];
    const float* w_lv       = (const float*)d_in[16];
    const float* b_lv       = (const float*)d_in[17];
    const float* w_dec      = (const float*)d_in[18];
    const float* b_dec      = (const float*)d_in[19];
    const float* veps       = (const float*)d_in[20];
    const float* w1         = (const float*)d_in[21];
    const float* a_src1     = (const float*)d_in[22];
    const float* a_dst1     = (const float*)d_in[23];
    const float* b1         = (const float*)d_in[24];
    const float* w2         = (const float*)d_in[25];
    const float* a_src2     = (const float*)d_in[26];
    const float* a_dst2     = (const float*)d_in[27];
    const float* b2         = (const float*)d_in[28];
    float* out = (float*)d_out;

    // ---- workspace (byte offsets) ----
    char* wsb = (char*)d_ws;
    bf16_t* temb_bf = (bf16_t*)(wsb + 0);                 // 19.2 MB
    bf16_t* Gi0     = (bf16_t*)(wsb + 19200000);          // 36.86 MB
    bf16_t* Gi1     = (bf16_t*)(wsb + 56064000);          // 36.86 MB (ends 92,928,000)
    float*  mlbuf   = (float*)(wsb + 56064000);           // VAE alias in Gi1
    float*  recb    = (float*)(wsb + 64256000);
    bf16_t* xp1b    = (bf16_t*)(wsb + 0);                 // GAT alias in temb
    bf16_t* x1b     = (bf16_t*)(wsb + 20480000);
    float*  xp2     = (float*)(wsb + 30720000);
    bf16_t* wih0_bf = (bf16_t*)(wsb + 92928000);
    bf16_t* whh0_bf = (bf16_t*)(wsb + 93419520);
    bf16_t* wih1_bf = (bf16_t*)(wsb + 93812736);
    bf16_t* whh1_bf = (bf16_t*)(wsb + 94205952);
    bf16_t* wml_bf  = (bf16_t*)(wsb + 94599168);
    bf16_t* wdec_bf = (bf16_t*)(wsb + 95123456);
    bf16_t* w1t_bf  = (bf16_t*)(wsb + 95385600);
    bf16_t* w2t_bf  = (bf16_t*)(wsb + 95648000);
    float*  b_ml    = (float*)(wsb + 95750400);
    bf16_t* ufeats_bf = (bf16_t*)(wsb + 95752448);
    bf16_t* out0    = (bf16_t*)(wsb + 99848448);          // 4 slots x 3,072,000
    bf16_t* h0b_init = (bf16_t*)(wsb + 124424448);
    bf16_t* h1init  = (bf16_t*)(wsb + 127496448);
    bf16_t* h1sA    = (bf16_t*)(wsb + 130568448);
    bf16_t* h1sB    = (bf16_t*)(wsb + 133640448);
    bf16_t* xin_bf  = (bf16_t*)(wsb + 136712448);
    int*    deg     = (int*)(wsb + 141832448);
    int*    dcnt    = (int*)(wsb + 141872448);
    int*    rowptr  = (int*)(wsb + 141912448);
    int*    csrc    = (int*)(wsb + 141952512);
    float*  asn1    = (float*)(wsb + 142312512);
    float*  adn1    = (float*)(wsb + 142632512);
    float*  asn2    = (float*)(wsb + 142952512);
    float*  adn2    = (float*)(wsb + 142992512);

    const int TB = 256;
    auto blocks = [](int n) { return (n + 255) / 256; };

    auto mkcfg = [](const bf16_t* A, const bf16_t* B, const float* bias,
                    float* Cf, bf16_t* Cb, int M, int N, int K, int ldc,
                    const int* gtok, int t0) {
        GCfg g; g.A = A; g.B = B; g.bias = bias; g.Cf = Cf; g.Cb = Cb;
        g.M = M; g.N = N; g.K = K; g.ldc = ldc; g.gtok = gtok; g.t0 = t0;
        return g;
    };
    auto launch_bf = [&](GCfg g0, GCfg g1, int z) {
        dim3 grid((g0.N + 127) / 128, (g0.M + 127) / 128, z);
        hipLaunchKernelGGL((mfma_gemm<true>), grid, dim3(TB), 0, stream, g0, g1);
    };
    auto launch_f32 = [&](GCfg g0) {
        dim3 grid((g0.N + 127) / 128, (g0.M + 127) / 128, 1);
        hipLaunchKernelGGL((mfma_gemm<false>), grid, dim3(TB), 0, stream, g0, g0);
    };

    // ---- prep ----
    PrepArgs pa;
    auto seg = [&](int k, const float* s, bf16_t* dst, int rows, int cin, int cout, int tr) {
        pa.seg[k] = SegD{s, dst, rows, cin, cout, tr};
    };
    seg(0, temb, temb_bf, V_, D_, DP_, 0);
    seg(1, w_ih0, wih0_bf, 3 * H_, D_, DP_, 0);
    seg(2, w_hh0, whh0_bf, 3 * H_, H_, H_, 0);
    seg(3, w_ih1, wih1_bf, 3 * H_, H_, H_, 0);
    seg(4, w_hh1, whh1_bf, 3 * H_, H_, H_, 0);
    seg(5, w_mu, wml_bf, Z_, F_, F_, 0);
    seg(6, w_lv, wml_bf + (size_t)Z_ * F_, Z_, F_, F_, 0);
    seg(7, w_dec, wdec_bf, F_, Z_, Z_, 0);
    seg(8, user_feats, ufeats_bf, NU_, F_, F_, 0);
    seg(9, w1, w1t_bf, HEADS_ * H1_, 0, H_, 1);
    seg(10, w2, w2t_bf, H2_, 0, HEADS_ * H1_, 1);
    pa.nseg = 11;
    long long acc = 0;
    for (int k = 0; k < 11; k++) {
        pa.base[k] = acc;
        acc += (long long)pa.seg[k].rows * pa.seg[k].cout;
    }
    pa.base[11] = acc;
    pa.total = acc;
    hipLaunchKernelGGL(prep_kern, dim3(6144), dim3(TB), 0, stream, pa);

    hipLaunchKernelGGL(init_all, dim3(blocks(NT_ * H_)), dim3(TB), 0, stream,
                       h0in, h0b_init, h1init,
                       deg, dcnt, out + N_ * H2_, b_ml, b_mu, b_lv);

    // ---- CSR build ----
    hipLaunchKernelGGL(csr_hist, dim3(blocks(E2_)), dim3(TB), 0, stream, ei, deg);
    hipLaunchKernelGGL(csr_scan, dim3(1), dim3(TB), 0, stream, deg, rowptr);
    hipLaunchKernelGGL(csr_scatter, dim3(blocks(E2_)), dim3(TB), 0, stream,
                       ei, rowptr, dcnt, csrc);

    // ---- VAE ----
    launch_f32(mkcfg(ufeats_bf, wml_bf, b_ml, mlbuf, nullptr,
                     NU_, 2 * Z_, F_, 2 * Z_, nullptr, 0));
    bf16_t* z_bf = xin_bf + (size_t)B_ * H_;
    hipLaunchKernelGGL(vae_z_kl, dim3(256), dim3(TB), 0, stream,
                       mlbuf, veps, z_bf, out + N_ * H2_);
    launch_f32(mkcfg(z_bf, wdec_bf, b_dec, recb, nullptr,
                     NU_, F_, Z_, F_, nullptr, 0));
    hipLaunchKernelGGL(rec_loss_kern, dim3(256), dim3(TB), 0, stream,
                       recb, user_feats, out + N_ * H2_ + 1);

    // ---- 2-layer GRU: paired chunk gi GEMMs + paired per-step recurrence ----
    const int MC = TCH_ * NT_;
    auto giL0 = [&](int c) {
        return mkcfg(temb_bf, wih0_bf, b_ih0, nullptr, Gi0,
                     MC, 3 * H_, DP_, 3 * H_, gnf, 4 * c);
    };
    auto giL1 = [&]() {
        return mkcfg(out0, wih1_bf, b_ih1, nullptr, Gi1,
                     MC, 3 * H_, H_, 3 * H_, nullptr, 0);
    };
    auto recL0 = [&](int c, int s) -> RecLay {
        RecLay L;
        L.Gi = Gi0 + (size_t)s * NT_ * 3 * H_;
        L.Wh = whh0_bf; L.bhh = b_hh0;
        L.hprev = (c == 0 && s == 0) ? h0b_init
                : (s == 0) ? out0 + (size_t)3 * NT_ * H_
                           : out0 + (size_t)(s - 1) * NT_ * H_;
        L.hout = out0 + (size_t)s * NT_ * H_;
        return L;
    };
    auto recL1 = [&](int c, int s) -> RecLay {
        int t = 4 * c + s;
        RecLay L;
        L.Gi = Gi1 + (size_t)s * NT_ * 3 * H_;
        L.Wh = whh1_bf; L.bhh = b_hh1;
        L.hprev = (t == 0) ? h1init : (((t - 1) & 1) ? h1sB : h1sA);
        L.hout = (t & 1) ? h1sB : h1sA;
        return L;
    };

    // chunk 0: L0 only
    {
        GCfg g = giL0(0);
        launch_bf(g, g, 1);
    }
    for (int s = 0; s < TCH_; s++) {
        RecLay L = recL0(0, s);
        hipLaunchKernelGGL(gru_rec_step, dim3(H_ / 32, YB_), dim3(TB), 0, stream, L, L);
    }
    // chunks 1..5: paired GEMM then paired rec steps
    for (int c = 1; c < T_ / TCH_; c++) {
        launch_bf(giL1(), giL0(c), 2);
        for (int s = 0; s < TCH_; s++) {
            RecLay L0 = recL0(c, s), L1 = recL1(c - 1, s);
            hipLaunchKernelGGL(gru_rec_step, dim3(H_ / 32, 2 * YB_), dim3(TB), 0, stream,
                               L0, L1);
        }
    }
    // final: L1 chunk 5
    {
        GCfg g = giL1();
        launch_bf(g, g, 1);
    }
    for (int s = 0; s < TCH_; s++) {
        RecLay L = recL1(T_ / TCH_ - 1, s);
        hipLaunchKernelGGL(gru_rec_step, dim3(H_ / 32, YB_), dim3(TB), 0, stream, L, L);
    }

    // ---- assemble x_in (final h1 state is h1sB: t=23 odd) ----
    hipLaunchKernelGGL(assemble_xin, dim3(blocks(NT_ * H_)), dim3(TB), 0, stream,
                       h1sB, xin_bf);

    // ---- GAT layer 1 (xp1 in bf16) ----
    launch_bf(mkcfg(xin_bf, w1t_bf, nullptr, nullptr, xp1b,
                    N_, HEADS_ * H1_, H_, HEADS_ * H1_, nullptr, 0),
              mkcfg(xin_bf, w1t_bf, nullptr, nullptr, xp1b,
                    N_, HEADS_ * H1_, H_, HEADS_ * H1_, nullptr, 0), 1);
    hipLaunchKernelGGL(gat_attn_coef_bf, dim3(blocks(N_ * HEADS_)), dim3(TB), 0, stream,
                       xp1b, a_src1, a_dst1, asn1, adn1, HEADS_, H1_);
    hipLaunchKernelGGL(gat_agg1, dim3(N_), dim3(TB), 0, stream,
                       rowptr, csrc, asn1, adn1, xp1b, b1, x1b);

    // ---- GAT layer 2 ----
    launch_f32(mkcfg(x1b, w2t_bf, nullptr, xp2, nullptr,
                     N_, H2_, HEADS_ * H1_, H2_, nullptr, 0));
    hipLaunchKernelGGL(gat_attn_coef, dim3(blocks(N_)), dim3(TB), 0, stream,
                       xp2, a_src2, a_dst2, asn2, adn2, 1, H2_);
    hipLaunchKernelGGL(gat_agg2, dim3((N_ + 3) / 4), dim3(TB), 0, stream,
                       rowptr, csrc, asn2, adn2, xp2, b2, out);

    (void)in_sizes; (void)n_in; (void)out_size; (void)ws_size;
}

// Round 10
// 1611.167 us; speedup vs baseline: 1.4127x; 1.0732x over previous
//
#include <hip/hip_runtime.h>

// ---- problem dims (fixed by reference) ----
#define V_ 30000
#define D_ 300
#define DP_ 320
#define T_ 24
#define H_ 256
#define NT_ 6000
#define NU_ 4000
#define N_ 10000
#define F_ 512
#define Z_ 256
#define E_ 80000
#define B_ 2000
#define H1_ 64
#define H2_ 100
#define HEADS_ 8
#define E2_ (E_ + N_)
#define TCH_ 4
#define YB_ 47          // row-blocks per layer in rec grid (47*128 >= 6000)

typedef __bf16 bf16_t;
typedef bf16_t bf16x8 __attribute__((ext_vector_type(8)));
typedef float  f32x4  __attribute__((ext_vector_type(4)));

// async global->LDS, 16B per lane; lds dest = base + lane*16 (wave-uniform base)
__device__ __forceinline__ void gll16(const bf16_t* g, bf16_t* l)
{
    __builtin_amdgcn_global_load_lds(
        (const __attribute__((address_space(1))) void*)g,
        (__attribute__((address_space(3))) void*)l, 16, 0, 0);
}

// =======================================================================
// 128x128 MFMA GEMM: C = A[M,K] @ B[N,K]^T (+bias).
// - double-buffered global_load_lds staging (1 barrier / K-iter)
// - bf16 C staged through XOR-swizzled LDS -> full-64B-line stores
// - XCD-aware block swizzle (R9: FETCH 84.5 -> 18.7 MB on paired chunk GEMMs)
// - gridDim.z picks cfg g0/g1 (two independent GEMMs in one launch).
// =======================================================================
struct GCfg {
    const bf16_t* A; const bf16_t* B; const float* bias;
    float* Cf; bf16_t* Cb; int M, N, K, ldc;
    const int* gtok; int t0;
};

template<bool OUTBF>
__global__ __launch_bounds__(256) void mfma_gemm(GCfg g0, GCfg g1)
{
    const GCfg g = blockIdx.z ? g1 : g0;
    __shared__ __align__(16) bf16_t SMEM[16384];   // 32 KB
    const int tid  = (int)threadIdx.x;
    const int wave = tid >> 6, lane = tid & 63;
    const int quad = lane >> 4, l16 = lane & 15;
    const int mq = (wave & 1) * 64, nq = (wave >> 1) * 64;

    int bx = (int)blockIdx.x, by = (int)blockIdx.y;
    {
        int gx = (int)gridDim.x, total = gx * (int)gridDim.y;
        if ((total & 7) == 0) {
            int L = by * gx + bx;
            int F = (L & 7) * (total >> 3) + (L >> 3);
            bx = F % gx;
            by = F / gx;
        }
    }
    const int mbase = by * 128, nbase = bx * 128;
    const int M = g.M, N = g.N, K = g.K, ldc = g.ldc;

    const bf16_t* agp[2];
    const bf16_t* bgp[2];
#pragma unroll
    for (int j = 0; j < 2; j++) {
        int i = wave * 128 + j * 64 + lane;
        int c = i >> 7, row = i & 127;
        int r = mbase + row; if (r >= M) r = M - 1;
        int src = g.gtok ? g.gtok[(r % NT_) * T_ + g.t0 + (r / NT_)] : r;
        agp[j] = g.A + (size_t)src * K + c * 8;
        int rb = nbase + row; if (rb >= N) rb = N - 1;
        bgp[j] = g.B + (size_t)rb * K + c * 8;
    }

    f32x4 acc[4][4];
#pragma unroll
    for (int mi = 0; mi < 4; mi++)
#pragma unroll
        for (int ni = 0; ni < 4; ni++) acc[mi][ni] = (f32x4){0.f, 0.f, 0.f, 0.f};

    auto stage = [&](int b, int k0) {
        bf16_t* ab = SMEM + b * 4096 + wave * 1024;
        bf16_t* bb = SMEM + 8192 + b * 4096 + wave * 1024;
        gll16(agp[0] + k0, ab);
        gll16(agp[1] + k0, ab + 512);
        gll16(bgp[0] + k0, bb);
        gll16(bgp[1] + k0, bb + 512);
    };

    const int niter = K >> 5;
    stage(0, 0);
    for (int ks = 0; ks < niter; ks++) {
        __syncthreads();
        if (ks + 1 < niter) stage((ks + 1) & 1, (ks + 1) * 32);
        const bf16_t* Ab = SMEM + (ks & 1) * 4096;
        const bf16_t* Bb = SMEM + 8192 + (ks & 1) * 4096;
        bf16x8 afr[4], bfr[4];
#pragma unroll
        for (int mi = 0; mi < 4; mi++)
            afr[mi] = *(const bf16x8*)(Ab + (size_t)(quad * 128 + mq + mi * 16 + l16) * 8);
#pragma unroll
        for (int ni = 0; ni < 4; ni++)
            bfr[ni] = *(const bf16x8*)(Bb + (size_t)(quad * 128 + nq + ni * 16 + l16) * 8);
#pragma unroll
        for (int mi = 0; mi < 4; mi++)
#pragma unroll
            for (int ni = 0; ni < 4; ni++)
                acc[mi][ni] = __builtin_amdgcn_mfma_f32_16x16x32_bf16(
                    afr[mi], bfr[ni], acc[mi][ni], 0, 0, 0);
    }

    if (OUTBF) {
        __syncthreads();
#pragma unroll
        for (int ni = 0; ni < 4; ni++) {
            int colc = nq + ni * 16 + l16;
            float bv = g.bias ? g.bias[nbase + colc] : 0.f;
            int cc = colc >> 3, off = colc & 7;
#pragma unroll
            for (int mi = 0; mi < 4; mi++)
#pragma unroll
                for (int r = 0; r < 4; r++) {
                    int row = mq + mi * 16 + quad * 4 + r;
                    int sw = (row ^ (row >> 3)) & 7;
                    SMEM[row * 128 + ((cc ^ sw) << 3) + off] =
                        (bf16_t)(acc[mi][ni][r] + bv);
                }
        }
        __syncthreads();
        {
            int row = tid >> 1, seg = tid & 1;
            int sw = (row ^ (row >> 3)) & 7;
            int growr = mbase + row;
            if (growr < M) {
#pragma unroll
                for (int q = 0; q < 8; q++) {
                    int cc = seg * 8 + q;
                    bf16x8 v = *(const bf16x8*)(SMEM + row * 128 + ((cc ^ sw) << 3));
                    *(bf16x8*)(g.Cb + (size_t)growr * ldc + nbase + cc * 8) = v;
                }
            }
        }
    } else {
#pragma unroll
        for (int ni = 0; ni < 4; ni++) {
            int col = nbase + nq + ni * 16 + l16;
            if (col >= N) continue;
            float bv = g.bias ? g.bias[col] : 0.f;
#pragma unroll
            for (int mi = 0; mi < 4; mi++)
#pragma unroll
                for (int r = 0; r < 4; r++) {
                    int row = mbase + mq + mi * 16 + quad * 4 + r;
                    if (row >= M) continue;
                    g.Cf[(size_t)row * ldc + col] = acc[mi][ni][r] + bv;
                }
        }
    }
}

// =======================================================================
// Per-step GRU recurrence, bf16 state. One launch carries TWO independent
// layer-steps via blockIdx.y halves. Wh B-fragments in VGPRs; h-tile
// double-buffered via global_load_lds. NEW (R10): the epilogue Gi slice
// (128 rows x 3 gates x 32 cols = 24KB) is ALSO staged via global_load_lds
// (64B-contiguous segments) and gates are read from LDS — replaces the
// 48 scalar 2-byte global loads/thread whose 32B-sector inflation made
// rec steps the dominant time pool (~1000us inferred at R9).
// =======================================================================
struct RecLay {
    const bf16_t* Gi;      // [NT][768] bf16 (b_ih fused)
    const bf16_t* Wh;      // [768][256]
    const float*  bhh;
    const bf16_t* hprev;   // [NT][256] bf16
    bf16_t*       hout;    // [NT][256] bf16
};

__global__ __launch_bounds__(256) void gru_rec_step(RecLay A0, RecLay A1)
{
    const bool second = (blockIdx.y >= YB_);
    const RecLay L = second ? A1 : A0;
    const int byr = second ? (int)blockIdx.y - YB_ : (int)blockIdx.y;

    __shared__ __align__(16) bf16_t SMEM[12288];   // 24 KB
    const int tid  = (int)threadIdx.x;
    const int wave = tid >> 6, lane = tid & 63;
    const int quad = lane >> 4, l16 = lane & 15;
    const int rw = wave & 1, cw = wave >> 1;
    const int bm = byr * 128;
    const int bn = blockIdx.x * 32;
    const int col = bn + cw * 16 + l16;

    bf16x8 wfr[3][8];
#pragma unroll
    for (int g = 0; g < 3; g++) {
        const bf16_t* wrow = L.Wh + (size_t)(g * H_ + col) * H_ + quad * 8;
#pragma unroll
        for (int ks = 0; ks < 8; ks++)
            wfr[g][ks] = *(const bf16x8*)(wrow + ks * 32);
    }

    const bf16_t* hgp[2];
#pragma unroll
    for (int j = 0; j < 2; j++) {
        int i = wave * 128 + j * 64 + lane;
        int c = i >> 7, row = i & 127;
        int rg = bm + row; if (rg >= NT_) rg = NT_ - 1;
        hgp[j] = L.hprev + (size_t)rg * H_ + c * 8;
    }

    auto stage = [&](int b, int k0) {
        bf16_t* lb = SMEM + b * 4096 + wave * 1024;
        gll16(hgp[0] + k0, lb);
        gll16(hgp[1] + k0, lb + 512);
    };

    const float bhr = L.bhh[col], bhz = L.bhh[H_ + col], bhn = L.bhh[2 * H_ + col];

    f32x4 acc[4][3];
#pragma unroll
    for (int mi = 0; mi < 4; mi++)
#pragma unroll
        for (int g = 0; g < 3; g++) acc[mi][g] = (f32x4){0.f, 0.f, 0.f, 0.f};

    stage(0, 0);
#pragma unroll
    for (int ks = 0; ks < 8; ks++) {
        __syncthreads();
        if (ks < 7) stage((ks + 1) & 1, (ks + 1) * 32);
        const bf16_t* Ab = SMEM + (ks & 1) * 4096;
        bf16x8 afr[4];
#pragma unroll
        for (int mi = 0; mi < 4; mi++)
            afr[mi] = *(const bf16x8*)(Ab + (size_t)(quad * 128 + rw * 64 + mi * 16 + l16) * 8);
#pragma unroll
        for (int mi = 0; mi < 4; mi++)
#pragma unroll
            for (int g = 0; g < 3; g++)
                acc[mi][g] = __builtin_amdgcn_mfma_f32_16x16x32_bf16(
                    afr[mi], wfr[g][ks], acc[mi][g], 0, 0, 0);
    }

    // hold values (scattered but only 16 x 2B per thread, L2-hot)
    float hold[4][4];
#pragma unroll
    for (int mi = 0; mi < 4; mi++)
#pragma unroll
        for (int r = 0; r < 4; r++) {
            int m = bm + rw * 64 + mi * 16 + quad * 4 + r;
            int mc = m < NT_ ? m : NT_ - 1;
            hold[mi][r] = (float)L.hprev[(size_t)mc * H_ + col];
        }

    // ---- stage Gi slice into LDS: gate g at SMEM[g*4096 + row*32 + c] ----
    __syncthreads();      // all staging-buffer reads done; reuse SMEM
    {
        int t = wave * 2;  // wave handles row-groups [t*16,+16) and [(t+1)*16,+16)
#pragma unroll
        for (int j = 0; j < 2; j++) {
            int rowb = (t + j) * 16 + (lane >> 2);
            int rg = bm + rowb; if (rg >= NT_) rg = NT_ - 1;
            const bf16_t* gbase = L.Gi + (size_t)rg * (3 * H_) + bn + (lane & 3) * 8;
#pragma unroll
            for (int g = 0; g < 3; g++)
                gll16(gbase + g * H_, SMEM + g * 4096 + (t + j) * 512);
        }
    }
    __syncthreads();

    float hv[4][4];
#pragma unroll
    for (int mi = 0; mi < 4; mi++)
#pragma unroll
        for (int r = 0; r < 4; r++) {
            int row_l = rw * 64 + mi * 16 + quad * 4 + r;
            int col_l = cw * 16 + l16;
            float ir  = (float)SMEM[row_l * 32 + col_l];
            float iz  = (float)SMEM[4096 + row_l * 32 + col_l];
            float in_ = (float)SMEM[8192 + row_l * 32 + col_l];
            float hr = acc[mi][0][r] + bhr;
            float hz = acc[mi][1][r] + bhz;
            float hn = acc[mi][2][r] + bhn;
            float rg = 1.f / (1.f + expf(-(ir + hr)));
            float zg = 1.f / (1.f + expf(-(iz + hz)));
            float ng = tanhf(in_ + rg * hn);
            hv[mi][r] = (1.f - zg) * ng + zg * hold[mi][r];
        }
    __syncthreads();
#pragma unroll
    for (int mi = 0; mi < 4; mi++)
#pragma unroll
        for (int r = 0; r < 4; r++) {
            int row_l = rw * 64 + mi * 16 + quad * 4 + r;
            SMEM[row_l * 40 + cw * 16 + l16] = (bf16_t)hv[mi][r];
        }
    __syncthreads();
    for (int t = tid; t < 512; t += 256) {
        int row_l = t >> 2, q = t & 3;
        int rg = bm + row_l;
        if (rg < NT_) {
            bf16x8 v = *(const bf16x8*)(SMEM + row_l * 40 + q * 8);
            *(bf16x8*)(L.hout + (size_t)rg * H_ + bn + q * 8) = v;
        }
    }
}

// ---------------- prep: all f32->bf16 conversions in one launch ----------------
struct SegD { const float* src; bf16_t* dst; int rows, cin, cout, transp; };
struct PrepArgs { SegD seg[11]; long long base[12]; int nseg; long long total; };

__global__ void prep_kern(PrepArgs pa)
{
    long long stride = (long long)gridDim.x * blockDim.x;
    for (long long i = (long long)blockIdx.x * blockDim.x + threadIdx.x;
         i < pa.total; i += stride) {
        int k = 0;
        while (k + 1 < pa.nseg && i >= pa.base[k + 1]) k++;
        long long local = i - pa.base[k];
        SegD sg = pa.seg[k];
        int r = (int)(local / sg.cout);
        int c = (int)(local - (long long)r * sg.cout);
        float v;
        if (sg.transp) v = sg.src[(size_t)c * sg.rows + r];
        else           v = (c < sg.cin) ? sg.src[(size_t)r * sg.cin + c] : 0.f;
        sg.dst[local] = (bf16_t)v;
    }
}

// ---------------- fused init ----------------
__global__ void init_all(const float* __restrict__ h0in, bf16_t* __restrict__ h0b,
                         bf16_t* __restrict__ h1b,
                         int* __restrict__ deg, int* __restrict__ dcnt,
                         float* __restrict__ loss2, float* __restrict__ b_ml,
                         const float* __restrict__ b_mu, const float* __restrict__ b_lv)
{
    int i = blockIdx.x * blockDim.x + threadIdx.x;
    if (i < NT_ * H_) {
        h0b[i] = (bf16_t)h0in[i];
        h1b[i] = (bf16_t)h0in[NT_ * H_ + i];
    }
    if (i < N_) { deg[i] = 0; dcnt[i] = 0; }
    if (i < 2 * Z_) b_ml[i] = (i < Z_) ? b_mu[i] : b_lv[i - Z_];
    if (i < 2) loss2[i] = 0.f;
}

// ---------------- CSR build (by dst, self-loops appended) ----------------
__device__ __forceinline__ void edge_sd(const int* __restrict__ ei, int e, int& s, int& d)
{
    if (e < E_) { s = ei[e]; d = ei[E_ + e]; }
    else        { s = d = e - E_; }
}

__global__ void csr_hist(const int* __restrict__ ei, int* __restrict__ deg)
{
    int e = blockIdx.x * blockDim.x + threadIdx.x;
    if (e >= E2_) return;
    int s, d; edge_sd(ei, e, s, d);
    atomicAdd(deg + d, 1);
}

__global__ void csr_scan(const int* __restrict__ deg, int* __restrict__ rowptr)
{
    __shared__ int buf[256];
    __shared__ int carry;
    int tid = (int)threadIdx.x;
    if (tid == 0) { carry = 0; rowptr[0] = 0; }
    __syncthreads();
    for (int c0 = 0; c0 < N_; c0 += 256) {
        int i = c0 + tid;
        buf[tid] = (i < N_) ? deg[i] : 0;
        __syncthreads();
        for (int off = 1; off < 256; off <<= 1) {
            int t = (tid >= off) ? buf[tid - off] : 0;
            __syncthreads();
            buf[tid] += t;
            __syncthreads();
        }
        if (i < N_) rowptr[i + 1] = carry + buf[tid];
        __syncthreads();
        if (tid == 255) carry += buf[255];
        __syncthreads();
    }
}

__global__ void csr_scatter(const int* __restrict__ ei, const int* __restrict__ rowptr,
                            int* __restrict__ dcnt, int* __restrict__ csrc)
{
    int e = blockIdx.x * blockDim.x + threadIdx.x;
    if (e >= E2_) return;
    int s, d; edge_sd(ei, e, s, d);
    int pos = rowptr[d] + atomicAdd(dcnt + d, 1);
    csrc[pos] = s;
}

// ---------------- VAE (grid-stride; 256 atomics) ----------------
__global__ __launch_bounds__(256) void vae_z_kl(
    const float* __restrict__ ml, const float* __restrict__ eps,
    bf16_t* __restrict__ z_out, float* __restrict__ kl_out)
{
    float t = 0.f;
    int stride = (int)gridDim.x * 256;
    for (int idx = blockIdx.x * 256 + threadIdx.x; idx < NU_ * Z_; idx += stride) {
        int row = idx >> 8, c = idx & 255;
        float m = ml[(size_t)row * 512 + c];
        float l = ml[(size_t)row * 512 + 256 + c];
        float el = expf(l);
        z_out[idx] = (bf16_t)(m + expf(0.5f * l) * eps[idx]);
        t += -0.5f * (1.f + l - m * m - el);
    }
    __shared__ float red[256];
    red[threadIdx.x] = t;
    __syncthreads();
    for (int s = 128; s > 0; s >>= 1) {
        if ((int)threadIdx.x < s) red[threadIdx.x] += red[threadIdx.x + s];
        __syncthreads();
    }
    if (threadIdx.x == 0) atomicAdd(kl_out, red[0] * (1.f / NU_));
}

__global__ __launch_bounds__(256) void rec_loss_kern(
    const float* __restrict__ rec, const float* __restrict__ uf,
    float* __restrict__ loss_out)
{
    float t = 0.f;
    int stride = (int)gridDim.x * 256;
    for (int idx = blockIdx.x * 256 + threadIdx.x; idx < NU_ * F_; idx += stride) {
        float d = rec[idx] - uf[idx];
        t += d * d;
    }
    __shared__ float red[256];
    red[threadIdx.x] = t;
    __syncthreads();
    for (int s = 128; s > 0; s >>= 1) {
        if ((int)threadIdx.x < s) red[threadIdx.x] += red[threadIdx.x + s];
        __syncthreads();
    }
    if (threadIdx.x == 0) atomicAdd(loss_out, red[0] * (1.f / (NU_ * F_)));
}

// ---------------- assemble x_in = [hn[:B], z, hn[B:]] (bf16 -> bf16) ----------------
__global__ void assemble_xin(const bf16_t* __restrict__ h1, bf16_t* __restrict__ x_in)
{
    int idx = blockIdx.x * blockDim.x + threadIdx.x;
    if (idx >= NT_ * H_) return;
    int row = idx >> 8, col = idx & 255;
    int dst = (row < B_) ? row : (row + NU_);
    x_in[(size_t)dst * H_ + col] = h1[idx];
}

// ---------------- GAT ----------------
__global__ void gat_attn_coef_bf(const bf16_t* __restrict__ xp,
                                 const float* __restrict__ a_src,
                                 const float* __restrict__ a_dst,
                                 float* __restrict__ asn, float* __restrict__ adn,
                                 int heads, int C)
{
    int i = blockIdx.x * blockDim.x + threadIdx.x;
    if (i >= N_ * heads) return;
    int node = i / heads, h = i - node * heads;
    const bf16_t* x = xp + (size_t)(node * heads + h) * C;
    float s = 0.f, d = 0.f;
    for (int c8 = 0; c8 < C; c8 += 8) {
        bf16x8 v = *(const bf16x8*)(x + c8);
#pragma unroll
        for (int j = 0; j < 8; j++) {
            float vv = (float)v[j];
            s += vv * a_src[h * C + c8 + j];
            d += vv * a_dst[h * C + c8 + j];
        }
    }
    asn[i] = s;
    adn[i] = d;
}

__global__ void gat_attn_coef(const float* __restrict__ xp, const float* __restrict__ a_src,
                              const float* __restrict__ a_dst, float* __restrict__ asn,
                              float* __restrict__ adn, int heads, int C)
{
    int i = blockIdx.x * blockDim.x + threadIdx.x;
    if (i >= N_ * heads) return;
    int node = i / heads, h = i - node * heads;
    const float* x = xp + (size_t)(node * heads + h) * C;
    float s = 0.f, d = 0.f;
    for (int c = 0; c < C; c++) {
        float v = x[c];
        s += v * a_src[h * C + c];
        d += v * a_dst[h * C + c];
    }
    asn[i] = s;
    adn[i] = d;
}

// fused edge-softmax + aggregate, layer 1: BLOCK per dst, all 8 heads.
__global__ __launch_bounds__(256) void gat_agg1(
    const int* __restrict__ rowptr, const int* __restrict__ csrc,
    const float* __restrict__ asn, const float* __restrict__ adn,
    const bf16_t* __restrict__ xp, const float* __restrict__ bias,
    bf16_t* __restrict__ x1out)
{
    int d = blockIdx.x;
    int tid = (int)threadIdx.x;
    int beg = rowptr[d], end = rowptr[d + 1];
    int h0 = tid >> 6, h1 = h0 + 4;
    float ad0 = adn[d * 8 + h0], ad1 = adn[d * 8 + h1];
    float mx0 = -1e30f, mx1 = -1e30f;
    for (int e = beg; e < end; e++) {
        int s = csrc[e];
        float l0 = asn[s * 8 + h0] + ad0; l0 = (l0 > 0.f) ? l0 : 0.2f * l0;
        float l1 = asn[s * 8 + h1] + ad1; l1 = (l1 > 0.f) ? l1 : 0.2f * l1;
        mx0 = fmaxf(mx0, l0); mx1 = fmaxf(mx1, l1);
    }
    float den0 = 0.f, den1 = 0.f, acc0 = 0.f, acc1 = 0.f;
    for (int e = beg; e < end; e++) {
        int s = csrc[e];
        float l0 = asn[s * 8 + h0] + ad0; l0 = (l0 > 0.f) ? l0 : 0.2f * l0;
        float l1 = asn[s * 8 + h1] + ad1; l1 = (l1 > 0.f) ? l1 : 0.2f * l1;
        float p0 = expf(l0 - mx0), p1 = expf(l1 - mx1);
        den0 += p0; den1 += p1;
        acc0 += p0 * (float)xp[(size_t)s * 512 + tid];
        acc1 += p1 * (float)xp[(size_t)s * 512 + 256 + tid];
    }
    x1out[(size_t)d * 512 + tid]       = (bf16_t)(bias[tid] + acc0 / den0);
    x1out[(size_t)d * 512 + 256 + tid] = (bf16_t)(bias[256 + tid] + acc1 / den1);
}

// fused edge-softmax + aggregate, layer 2 (1 head x 100ch): wave per dst
__global__ __launch_bounds__(256) void gat_agg2(
    const int* __restrict__ rowptr, const int* __restrict__ csrc,
    const float* __restrict__ asn, const float* __restrict__ adn,
    const float* __restrict__ xp, const float* __restrict__ bias,
    float* __restrict__ outp)
{
    int d = blockIdx.x * 4 + ((int)threadIdx.x >> 6);
    if (d >= N_) return;
    int lane = (int)threadIdx.x & 63;
    int beg = rowptr[d], end = rowptr[d + 1];
    float adnd = adn[d];
    float mx = -1e30f;
    for (int e = beg; e < end; e++) {
        float l = asn[csrc[e]] + adnd;
        l = (l > 0.f) ? l : 0.2f * l;
        mx = fmaxf(mx, l);
    }
    float den = 0.f, acc0 = 0.f, acc1 = 0.f;
    for (int e = beg; e < end; e++) {
        int s = csrc[e];
        float l = asn[s] + adnd;
        l = (l > 0.f) ? l : 0.2f * l;
        float p = expf(l - mx);
        den += p;
        acc0 += p * xp[(size_t)s * H2_ + lane];
        if (lane < H2_ - 64) acc1 += p * xp[(size_t)s * H2_ + 64 + lane];
    }
    outp[(size_t)d * H2_ + lane] = bias[lane] + acc0 / den;
    if (lane < H2_ - 64)
        outp[(size_t)d * H2_ + 64 + lane] = bias[64 + lane] + acc1 / den;
}

// ---------------- launcher ----------------
extern "C" void kernel_launch(void* const* d_in, const int* in_sizes, int n_in,
                              void* d_out, int out_size, void* d_ws, size_t ws_size,
                              hipStream_t stream)
{
    const float* user_feats = (const float*)d_in[1];
    const int*   gnf        = (const int*)d_in[2];
    const int*   ei         = (const int*)d_in[3];
    const float* temb       = (const float*)d_in[4];
    const float* w_ih0      = (const float*)d_in[5];
    const float* w_hh0      = (const float*)d_in[6];
    const float* b_ih0      = (const float*)d_in[7];
    const float* b_hh0      = (const float*)d_in[8];
    const float* w_ih1      = (const float*)d_in[9];
    const float* w_hh1      = (const float*)d_in[10];
    const float* b_ih1      = (const float*)d_in[11];
    const float* b_hh1      = (const float*)d_in[12];
    const float* h0in       = (const float*)d_in[13];
    const float* w_mu       = (const float*)d_in[14];
    const float* b_mu       = (const float*)d_in[15];
    const float* w_lv       = (const float*)d_in[16];
    const float* b_lv       = (const float*)d_in[17];
    const float* w_dec      = (const float*)d_in[18];
    const float* b_dec      = (const float*)d_in[19];
    const float* veps       = (const float*)d_in[20];
    const float* w1         = (const float*)d_in[21];
    const float* a_src1     = (const float*)d_in[22];
    const float* a_dst1     = (const float*)d_in[23];
    const float* b1         = (const float*)d_in[24];
    const float* w2         = (const float*)d_in[25];
    const float* a_src2     = (const float*)d_in[26];
    const float* a_dst2     = (const float*)d_in[27];
    const float* b2         = (const float*)d_in[28];
    float* out = (float*)d_out;

    // ---- workspace (byte offsets) ----
    char* wsb = (char*)d_ws;
    bf16_t* temb_bf = (bf16_t*)(wsb + 0);                 // 19.2 MB
    bf16_t* Gi0     = (bf16_t*)(wsb + 19200000);          // 36.86 MB
    bf16_t* Gi1     = (bf16_t*)(wsb + 56064000);          // 36.86 MB (ends 92,928,000)
    float*  mlbuf   = (float*)(wsb + 56064000);           // VAE alias in Gi1
    float*  recb    = (float*)(wsb + 64256000);
    bf16_t* xp1b    = (bf16_t*)(wsb + 0);                 // GAT alias in temb
    bf16_t* x1b     = (bf16_t*)(wsb + 20480000);
    float*  xp2     = (float*)(wsb + 30720000);
    bf16_t* wih0_bf = (bf16_t*)(wsb + 92928000);
    bf16_t* whh0_bf = (bf16_t*)(wsb + 93419520);
    bf16_t* wih1_bf = (bf16_t*)(wsb + 93812736);
    bf16_t* whh1_bf = (bf16_t*)(wsb + 94205952);
    bf16_t* wml_bf  = (bf16_t*)(wsb + 94599168);
    bf16_t* wdec_bf = (bf16_t*)(wsb + 95123456);
    bf16_t* w1t_bf  = (bf16_t*)(wsb + 95385600);
    bf16_t* w2t_bf  = (bf16_t*)(wsb + 95648000);
    float*  b_ml    = (float*)(wsb + 95750400);
    bf16_t* ufeats_bf = (bf16_t*)(wsb + 95752448);
    bf16_t* out0    = (bf16_t*)(wsb + 99848448);          // 4 slots x 3,072,000
    bf16_t* h0b_init = (bf16_t*)(wsb + 124424448);
    bf16_t* h1init  = (bf16_t*)(wsb + 127496448);
    bf16_t* h1sA    = (bf16_t*)(wsb + 130568448);
    bf16_t* h1sB    = (bf16_t*)(wsb + 133640448);
    bf16_t* xin_bf  = (bf16_t*)(wsb + 136712448);
    int*    deg     = (int*)(wsb + 141832448);
    int*    dcnt    = (int*)(wsb + 141872448);
    int*    rowptr  = (int*)(wsb + 141912448);
    int*    csrc    = (int*)(wsb + 141952512);
    float*  asn1    = (float*)(wsb + 142312512);
    float*  adn1    = (float*)(wsb + 142632512);
    float*  asn2    = (float*)(wsb + 142952512);
    float*  adn2    = (float*)(wsb + 142992512);

    const int TB = 256;
    auto blocks = [](int n) { return (n + 255) / 256; };

    auto mkcfg = [](const bf16_t* A, const bf16_t* B, const float* bias,
                    float* Cf, bf16_t* Cb, int M, int N, int K, int ldc,
                    const int* gtok, int t0) {
        GCfg g; g.A = A; g.B = B; g.bias = bias; g.Cf = Cf; g.Cb = Cb;
        g.M = M; g.N = N; g.K = K; g.ldc = ldc; g.gtok = gtok; g.t0 = t0;
        return g;
    };
    auto launch_bf = [&](GCfg g0, GCfg g1, int z) {
        dim3 grid((g0.N + 127) / 128, (g0.M + 127) / 128, z);
        hipLaunchKernelGGL((mfma_gemm<true>), grid, dim3(TB), 0, stream, g0, g1);
    };
    auto launch_f32 = [&](GCfg g0) {
        dim3 grid((g0.N + 127) / 128, (g0.M + 127) / 128, 1);
        hipLaunchKernelGGL((mfma_gemm<false>), grid, dim3(TB), 0, stream, g0, g0);
    };

    // ---- prep ----
    PrepArgs pa;
    auto seg = [&](int k, const float* s, bf16_t* dst, int rows, int cin, int cout, int tr) {
        pa.seg[k] = SegD{s, dst, rows, cin, cout, tr};
    };
    seg(0, temb, temb_bf, V_, D_, DP_, 0);
    seg(1, w_ih0, wih0_bf, 3 * H_, D_, DP_, 0);
    seg(2, w_hh0, whh0_bf, 3 * H_, H_, H_, 0);
    seg(3, w_ih1, wih1_bf, 3 * H_, H_, H_, 0);
    seg(4, w_hh1, whh1_bf, 3 * H_, H_, H_, 0);
    seg(5, w_mu, wml_bf, Z_, F_, F_, 0);
    seg(6, w_lv, wml_bf + (size_t)Z_ * F_, Z_, F_, F_, 0);
    seg(7, w_dec, wdec_bf, F_, Z_, Z_, 0);
    seg(8, user_feats, ufeats_bf, NU_, F_, F_, 0);
    seg(9, w1, w1t_bf, HEADS_ * H1_, 0, H_, 1);
    seg(10, w2, w2t_bf, H2_, 0, HEADS_ * H1_, 1);
    pa.nseg = 11;
    long long acc = 0;
    for (int k = 0; k < 11; k++) {
        pa.base[k] = acc;
        acc += (long long)pa.seg[k].rows * pa.seg[k].cout;
    }
    pa.base[11] = acc;
    pa.total = acc;
    hipLaunchKernelGGL(prep_kern, dim3(6144), dim3(TB), 0, stream, pa);

    hipLaunchKernelGGL(init_all, dim3(blocks(NT_ * H_)), dim3(TB), 0, stream,
                       h0in, h0b_init, h1init,
                       deg, dcnt, out + N_ * H2_, b_ml, b_mu, b_lv);

    // ---- CSR build ----
    hipLaunchKernelGGL(csr_hist, dim3(blocks(E2_)), dim3(TB), 0, stream, ei, deg);
    hipLaunchKernelGGL(csr_scan, dim3(1), dim3(TB), 0, stream, deg, rowptr);
    hipLaunchKernelGGL(csr_scatter, dim3(blocks(E2_)), dim3(TB), 0, stream,
                       ei, rowptr, dcnt, csrc);

    // ---- VAE ----
    launch_f32(mkcfg(ufeats_bf, wml_bf, b_ml, mlbuf, nullptr,
                     NU_, 2 * Z_, F_, 2 * Z_, nullptr, 0));
    bf16_t* z_bf = xin_bf + (size_t)B_ * H_;
    hipLaunchKernelGGL(vae_z_kl, dim3(256), dim3(TB), 0, stream,
                       mlbuf, veps, z_bf, out + N_ * H2_);
    launch_f32(mkcfg(z_bf, wdec_bf, b_dec, recb, nullptr,
                     NU_, F_, Z_, F_, nullptr, 0));
    hipLaunchKernelGGL(rec_loss_kern, dim3(256), dim3(TB), 0, stream,
                       recb, user_feats, out + N_ * H2_ + 1);

    // ---- 2-layer GRU: paired chunk gi GEMMs + paired per-step recurrence ----
    const int MC = TCH_ * NT_;
    auto giL0 = [&](int c) {
        return mkcfg(temb_bf, wih0_bf, b_ih0, nullptr, Gi0,
                     MC, 3 * H_, DP_, 3 * H_, gnf, 4 * c);
    };
    auto giL1 = [&]() {
        return mkcfg(out0, wih1_bf, b_ih1, nullptr, Gi1,
                     MC, 3 * H_, H_, 3 * H_, nullptr, 0);
    };
    auto recL0 = [&](int c, int s) -> RecLay {
        RecLay L;
        L.Gi = Gi0 + (size_t)s * NT_ * 3 * H_;
        L.Wh = whh0_bf; L.bhh = b_hh0;
        L.hprev = (c == 0 && s == 0) ? h0b_init
                : (s == 0) ? out0 + (size_t)3 * NT_ * H_
                           : out0 + (size_t)(s - 1) * NT_ * H_;
        L.hout = out0 + (size_t)s * NT_ * H_;
        return L;
    };
    auto recL1 = [&](int c, int s) -> RecLay {
        int t = 4 * c + s;
        RecLay L;
        L.Gi = Gi1 + (size_t)s * NT_ * 3 * H_;
        L.Wh = whh1_bf; L.bhh = b_hh1;
        L.hprev = (t == 0) ? h1init : (((t - 1) & 1) ? h1sB : h1sA);
        L.hout = (t & 1) ? h1sB : h1sA;
        return L;
    };

    // chunk 0: L0 only
    {
        GCfg g = giL0(0);
        launch_bf(g, g, 1);
    }
    for (int s = 0; s < TCH_; s++) {
        RecLay L = recL0(0, s);
        hipLaunchKernelGGL(gru_rec_step, dim3(H_ / 32, YB_), dim3(TB), 0, stream, L, L);
    }
    // chunks 1..5: paired GEMM then paired rec steps
    for (int c = 1; c < T_ / TCH_; c++) {
        launch_bf(giL1(), giL0(c), 2);
        for (int s = 0; s < TCH_; s++) {
            RecLay L0 = recL0(c, s), L1 = recL1(c - 1, s);
            hipLaunchKernelGGL(gru_rec_step, dim3(H_ / 32, 2 * YB_), dim3(TB), 0, stream,
                               L0, L1);
        }
    }
    // final: L1 chunk 5
    {
        GCfg g = giL1();
        launch_bf(g, g, 1);
    }
    for (int s = 0; s < TCH_; s++) {
        RecLay L = recL1(T_ / TCH_ - 1, s);
        hipLaunchKernelGGL(gru_rec_step, dim3(H_ / 32, YB_), dim3(TB), 0, stream, L, L);
    }

    // ---- assemble x_in (final h1 state is h1sB: t=23 odd) ----
    hipLaunchKernelGGL(assemble_xin, dim3(blocks(NT_ * H_)), dim3(TB), 0, stream,
                       h1sB, xin_bf);

    // ---- GAT layer 1 (xp1 in bf16) ----
    launch_bf(mkcfg(xin_bf, w1t_bf, nullptr, nullptr, xp1b,
                    N_, HEADS_ * H1_, H_, HEADS_ * H1_, nullptr, 0),
              mkcfg(xin_bf, w1t_bf, nullptr, nullptr, xp1b,
                    N_, HEADS_ * H1_, H_, HEADS_ * H1_, nullptr, 0), 1);
    hipLaunchKernelGGL(gat_attn_coef_bf, dim3(blocks(N_ * HEADS_)), dim3(TB), 0, stream,
                       xp1b, a_src1, a_dst1, asn1, adn1, HEADS_, H1_);
    hipLaunchKernelGGL(gat_agg1, dim3(N_), dim3(TB), 0, stream,
                       rowptr, csrc, asn1, adn1, xp1b, b1, x1b);

    // ---- GAT layer 2 ----
    launch_f32(mkcfg(x1b, w2t_bf, nullptr, xp2, nullptr,
                     N_, H2_, HEADS_ * H1_, H2_, nullptr, 0));
    hipLaunchKernelGGL(gat_attn_coef, dim3(blocks(N_)), dim3(TB), 0, stream,
                       xp2, a_src2, a_dst2, asn2, adn2, 1, H2_);
    hipLaunchKernelGGL(gat_agg2, dim3((N_ + 3) / 4), dim3(TB), 0, stream,
                       rowptr, csrc, asn2, adn2, xp2, b2, out);

    (void)in_sizes; (void)n_in; (void)out_size; (void)ws_size;
}